// Round 4
// baseline (1432.419 us; speedup 1.0000x reference)
//
#include <hip/hip_runtime.h>
#include <math.h>

#define DD 128
typedef unsigned short ushort_t;
typedef unsigned int uint_t;

// ---------------- DPP / swizzle wave-reduction helpers -------------------
template<int CTRL>
__device__ __forceinline__ float dppAdd(float x) {
    int y = __builtin_amdgcn_update_dpp(0, __float_as_int(x), CTRL, 0xF, 0xF, true);
    return x + __int_as_float(y);
}
// sum over 16-lane rows (result in every lane of the row)
__device__ __forceinline__ float red16(float x) {
    x = dppAdd<0xB1>(x);   // quad_perm(1,0,3,2)  = xor1
    x = dppAdd<0x4E>(x);   // quad_perm(2,3,0,1)  = xor2
    x = dppAdd<0x141>(x);  // row_half_mirror     = xor7 (other quad)
    x = dppAdd<0x140>(x);  // row_mirror          = xor15 (other octet)
    return x;
}
// exchange with lane^16 (within each 32-lane group)
__device__ __forceinline__ float swz16(float x) {
    return __int_as_float(__builtin_amdgcn_ds_swizzle(__float_as_int(x), 0x401F));
}

__device__ __forceinline__ ushort_t f2bf(float f) {
    uint_t u = __float_as_uint(f);
    u += 0x7FFFu + ((u >> 16) & 1u);
    return (ushort_t)(u >> 16);
}
__device__ __forceinline__ float bf2f(ushort_t h) {
    return __uint_as_float(((uint_t)h) << 16);
}

// ======================= CSR build (once per call) =======================
__global__ __launch_bounds__(256) void hist_kernel(const int* __restrict__ ei,
                                                   int* __restrict__ cnt, int E) {
    int i = blockIdx.x * 256 + threadIdx.x;
    if (i < E) atomicAdd(&cnt[ei[E + i]], 1);
}

__global__ __launch_bounds__(1024) void scan_kernel(const int* __restrict__ cnt,
                                                    int* __restrict__ row_start,
                                                    int* __restrict__ cursor, int N) {
    __shared__ int part[1024];
    const int tid = threadIdx.x;
    const int chunk = (N + 1023) >> 10;
    const int lo = min(N, tid * chunk);
    const int hi = min(N, lo + chunk);
    int s = 0;
    for (int i = lo; i < hi; ++i) s += cnt[i];
    part[tid] = s;
    __syncthreads();
    for (int off = 1; off < 1024; off <<= 1) {
        int val = 0;
        if (tid >= off) val = part[tid - off];
        __syncthreads();
        part[tid] += val;
        __syncthreads();
    }
    int run = (tid == 0) ? 0 : part[tid - 1];
    for (int i = lo; i < hi; ++i) {
        row_start[i] = run; cursor[i] = run;
        run += cnt[i];
    }
    if (tid == 1023) row_start[N] = part[1023];
}

// PRE path: group-per-edge; writes srcp + bf16 edge_attr stream in CSR order.
__global__ __launch_bounds__(256) void scatter_pre_kernel(
    const int* __restrict__ ei, const float* __restrict__ lu, const float* __restrict__ t,
    const float* __restrict__ msg, const float* __restrict__ time_w,
    const float* __restrict__ time_b, int* __restrict__ cursor,
    int* __restrict__ srcp, ushort_t* __restrict__ eaA, uint_t* __restrict__ eaB, int E)
{
    const int g = threadIdx.x >> 5, l = threadIdx.x & 31;
    int i = blockIdx.x * 8 + g;
    if (i >= E) return;
    const int s = ei[i], d = ei[E + i];
    int pos = 0;
    if (l == 0) pos = atomicAdd(&cursor[d], 1);
    pos = __shfl(pos, 0, 32);
    const float rel = lu[s] - t[i];
    const float eac = cosf(rel * time_w[l] + time_b[l]);
    const float2 m2 = ((const float2*)msg)[(size_t)i * 32 + l];
    eaA[(size_t)pos * 32 + l] = f2bf(eac);
    eaB[(size_t)pos * 32 + l] = (uint_t)f2bf(m2.x) | ((uint_t)f2bf(m2.y) << 16);
    if (l == 0) srcp[pos] = s;
}

// FB path: as before (src,eid) + rel
__global__ __launch_bounds__(256) void scatter_fb_kernel(
    const int* __restrict__ ei, const float* __restrict__ lu, const float* __restrict__ t,
    int* __restrict__ cursor, int2* __restrict__ se, float* __restrict__ relp, int E)
{
    int i = blockIdx.x * 256 + threadIdx.x;
    if (i < E) {
        int s = ei[i], d = ei[E + i];
        int pos = atomicAdd(&cursor[d], 1);
        se[pos] = make_int2(s, i);
        relp[pos] = lu[s] - t[i];
    }
}

// ======================= Wu = Wq @ B,  bu = bq @ B =======================
__global__ __launch_bounds__(256) void build_wu_kernel(
    const float* __restrict__ Wq, const float* __restrict__ bq,
    const float* __restrict__ We, float* __restrict__ Wu, float* __restrict__ bu)
{
    int idx = blockIdx.x * 256 + threadIdx.x;   // [0, 32768)
    int h = idx >> 14;
    int r = (idx >> 7) & 127;
    int col = idx & 127;
    int l = col >> 2, kk = col & 3;
    int dim = (kk == 0) ? l : (kk == 1) ? (32 + 2 * l) : (33 + 2 * l);
    float s = 0.f, sb = 0.f;
    if (kk < 3) {
        for (int c = 0; c < 64; ++c) {
            float wv = We[dim * 128 + h * 64 + c];
            s += Wq[r * 128 + h * 64 + c] * wv;
            if (r == 0) sb += bq[h * 64 + c] * wv;
        }
    }
    Wu[(h * 128 + r) * 128 + col] = s;
    if (r == 0) bu[h * 128 + col] = sb;
}

// ======================= fused 6-way node GEMM (K=128, N=128) ============
__global__ __launch_bounds__(256) void gemm6_kernel(
    const float* __restrict__ X,
    const float* __restrict__ W0, const float* __restrict__ W1,
    const float* __restrict__ W2, const float* __restrict__ W3,
    const float* __restrict__ W4, const float* __restrict__ W5,
    const float* __restrict__ b0, const float* __restrict__ b1,
    const float* __restrict__ b2, const float* __restrict__ b3,
    const float* __restrict__ b4, const float* __restrict__ b5,
    float* __restrict__ O0, float* __restrict__ O1,
    float* __restrict__ O2, float* __restrict__ O3,
    float* __restrict__ O4, float* __restrict__ O5, int M)
{
    __shared__ float Xs[32 * 128];
    __shared__ float Wsh[128 * 128];
    const int which = blockIdx.y;
    const float* W; const float* bias; float* O; int ostr;
    switch (which) {
        case 0: W = W0; bias = b0; O = O0; ostr = 32; break;
        case 1: W = W1; bias = b1; O = O1; ostr = 32; break;
        case 2: W = W2; bias = b2; O = O2; ostr = 32; break;
        case 3: W = W3; bias = b3; O = O3; ostr = 32; break;
        case 4: W = W4; bias = b4; O = O4; ostr = 64; break;
        default: W = W5; bias = b5; O = O5; ostr = 64; break;
    }
    const int tid = threadIdx.x;
    const int m0 = blockIdx.x * 32;

    {
        const float4* Wg = (const float4*)W;
        float4* Wl = (float4*)Wsh;
        #pragma unroll
        for (int i = 0; i < 16; ++i) Wl[tid + i * 256] = Wg[tid + i * 256];
    }
    {
        float4* Xl = (float4*)Xs;
        const float4* Xg = (const float4*)X;
        #pragma unroll
        for (int i = 0; i < 4; ++i) {
            int f = tid + i * 256;
            int r = f >> 5, c4 = f & 31;
            int row = m0 + r;
            float4 val = make_float4(0.f, 0.f, 0.f, 0.f);
            if (row < M) val = Xg[(size_t)row * 32 + c4];
            Xl[f] = val;
        }
    }
    __syncthreads();

    const int tr = tid >> 5, tc = tid & 31;
    const int r0 = tr * 4, c0 = tc * 4;
    float acc[4][4] = {};
    #pragma unroll 4
    for (int kk = 0; kk < 128; ++kk) {
        float4 bb = *(const float4*)&Wsh[kk * 128 + c0];
        #pragma unroll
        for (int i = 0; i < 4; ++i) {
            float a = Xs[(r0 + i) * 128 + kk];
            acc[i][0] += a * bb.x; acc[i][1] += a * bb.y;
            acc[i][2] += a * bb.z; acc[i][3] += a * bb.w;
        }
    }
    float4 bias4 = *(const float4*)&bias[c0];
    #pragma unroll
    for (int i = 0; i < 4; ++i) {
        int row = m0 + r0 + i;
        if (row < M) {
            float4 o;
            o.x = acc[i][0] + bias4.x; o.y = acc[i][1] + bias4.y;
            o.z = acc[i][2] + bias4.z; o.w = acc[i][3] + bias4.w;
            ((float4*)O)[(size_t)row * ostr + tc] = o;
        }
    }
}

// ======================= node-centric attention ==========================
// PRE=1: sequential bf16 edge_attr stream (eaA/eaB) + srcp; PRE=0: gather
// msg by eid + on-the-fly cos. DPP reductions; meta prefetched 1 chunk ahead.
template<int PRE>
__global__ __launch_bounds__(256) void node_attn_kernel(
    const int* __restrict__ row_start,
    const int* __restrict__ srcp, const ushort_t* __restrict__ eaA,
    const uint_t* __restrict__ eaB,
    const int2* __restrict__ se, const float* __restrict__ relp,
    const float* __restrict__ msg,
    const float* __restrict__ time_w, const float* __restrict__ time_b,
    const float* __restrict__ q, const float* __restrict__ k,
    const float* __restrict__ v, const float* __restrict__ u,
    const float* __restrict__ We, const float* __restrict__ skip,
    float* __restrict__ outp, float* __restrict__ bn_sum, float* __restrict__ bn_ssq,
    int N, int do_bn)
{
    __shared__ float WeS[96 * 128];   // 48 KB
    const int tid = threadIdx.x;
    {
        const float4* Wg = (const float4*)We;
        float4* Wl = (float4*)WeS;
        #pragma unroll
        for (int i = 0; i < 12; ++i) Wl[tid + i * 256] = Wg[tid + i * 256];
    }
    const int g = tid >> 5, l = tid & 31;
    const float twl = time_w[l];
    const float tbl = time_b[l];
    __syncthreads();

    const float4* K4 = (const float4*)k;
    const float4* V4 = (const float4*)v;
    const float4* Q4 = (const float4*)q;
    const float4* U4 = (const float4*)u;
    const float2* M2 = (const float2*)msg;
    const float4* S4 = (const float4*)skip;
    const float4* WeS4 = (const float4*)WeS;

    float4 bsum = {0,0,0,0}, bssq = {0,0,0,0};

    for (int n = blockIdx.x * 8 + g; n < N; n += gridDim.x * 8) {
        const int e0 = row_start[n], e1 = row_start[n + 1];
        const float4 q4 = Q4[(size_t)n * 32 + l];
        const float4 u0 = U4[(size_t)n * 64 + l];
        const float4 u1 = U4[(size_t)n * 64 + 32 + l];
        float4 wv = {0,0,0,0};
        float sea0x = 0.f, sea0y = 0.f, sea0z = 0.f;
        float sea1x = 0.f, sea1y = 0.f, sea1z = 0.f;
        float den0 = 0.f, den1 = 0.f;

        int srcsC[4], eidC[4];
        float relC[4];
        // prologue meta load (chunk 0)
        if (e0 < e1) {
            #pragma unroll
            for (int j = 0; j < 4; ++j) {
                int idx = min(e0 + j, e1 - 1);
                if (PRE) { srcsC[j] = srcp[idx]; }
                else { int2 s2 = se[idx]; srcsC[j] = s2.x; eidC[j] = s2.y; relC[j] = relp[idx]; }
            }
        }

        for (int base = e0; base < e1; base += 4) {
            // issue gathers for current chunk first (longest latency)
            float4 k4v[4], v4v[4];
            #pragma unroll
            for (int j = 0; j < 4; ++j) {
                k4v[j] = K4[(size_t)srcsC[j] * 32 + l];
                v4v[j] = V4[(size_t)srcsC[j] * 32 + l];
            }
            // edge_attr for current chunk
            float eac[4], mx[4], my[4];
            if (PRE) {
                #pragma unroll
                for (int j = 0; j < 4; ++j) {
                    size_t p = (size_t)min(base + j, e1 - 1) * 32 + l;
                    ushort_t a = eaA[p];
                    uint_t  b = eaB[p];
                    eac[j] = bf2f(a);
                    mx[j] = bf2f((ushort_t)(b & 0xFFFFu));
                    my[j] = bf2f((ushort_t)(b >> 16));
                }
            } else {
                #pragma unroll
                for (int j = 0; j < 4; ++j) {
                    float2 m2 = M2[(size_t)eidC[j] * 32 + l];
                    eac[j] = cosf(relC[j] * twl + tbl);
                    mx[j] = m2.x; my[j] = m2.y;
                }
            }
            // prefetch meta for next chunk
            int srcsN[4], eidN[4];
            float relN[4];
            const int nbase = (base + 4 < e1) ? base + 4 : base;
            #pragma unroll
            for (int j = 0; j < 4; ++j) {
                int idx = min(nbase + j, e1 - 1);
                if (PRE) { srcsN[j] = srcp[idx]; }
                else { int2 s2 = se[idx]; srcsN[j] = s2.x; eidN[j] = s2.y; relN[j] = relp[idx]; }
            }

            float pq[4], pa[4], pb[4];
            #pragma unroll
            for (int j = 0; j < 4; ++j) {
                pq[j] = q4.x*k4v[j].x + q4.y*k4v[j].y + q4.z*k4v[j].z + q4.w*k4v[j].w;
                pa[j] = eac[j]*u0.x + mx[j]*u0.y + my[j]*u0.z;
                pb[j] = eac[j]*u1.x + mx[j]*u1.y + my[j]*u1.z;
            }
            // DPP 16-lane sums (VALU latency, no LDS)
            #pragma unroll
            for (int j = 0; j < 4; ++j) {
                pq[j] = red16(pq[j]); pa[j] = red16(pa[j]); pb[j] = red16(pb[j]);
            }
            // single cross-16 exchange stage (all 12 swizzles independent)
            #pragma unroll
            for (int j = 0; j < 4; ++j) {
                const float pqo = swz16(pq[j]);
                const float paf = pa[j] + swz16(pa[j]);
                const float pbf = pb[j] + swz16(pb[j]);
                const float qk0 = (l < 16) ? pq[j] : pqo;
                const float qk1 = (l < 16) ? pqo : pq[j];
                float w0 = __expf((qk0 + paf) * 0.125f);
                float w1 = __expf((qk1 + pbf) * 0.125f);
                if (base + j >= e1) { w0 = 0.f; w1 = 0.f; }
                den0 += w0; den1 += w1;
                const float wh = (l < 16) ? w0 : w1;
                wv.x += wh*v4v[j].x; wv.y += wh*v4v[j].y;
                wv.z += wh*v4v[j].z; wv.w += wh*v4v[j].w;
                sea0x += w0*eac[j]; sea0y += w0*mx[j]; sea0z += w0*my[j];
                sea1x += w1*eac[j]; sea1y += w1*mx[j]; sea1z += w1*my[j];
            }
            #pragma unroll
            for (int j = 0; j < 4; ++j) {
                srcsC[j] = srcsN[j];
                if (!PRE) { eidC[j] = eidN[j]; relC[j] = relN[j]; }
            }
        }

        // e_fin[c] = sum_j sea_h[j] * We[j][h*64+c]  (lane's 4 channels)
        float4 ef = {0,0,0,0};
        #pragma unroll
        for (int j = 0; j < 96; ++j) {
            const int owner = (j < 32) ? j : ((j - 32) >> 1);
            float c0, c1;
            if (j < 32)                    { c0 = sea0x; c1 = sea1x; }
            else if (((j - 32) & 1) == 0)  { c0 = sea0y; c1 = sea1y; }
            else                           { c0 = sea0z; c1 = sea1z; }
            const float s0 = __shfl(c0, owner, 32);
            const float s1 = __shfl(c1, owner, 32);
            const float sj = (l < 16) ? s0 : s1;
            const float4 w4 = WeS4[j * 32 + l];
            ef.x += sj*w4.x; ef.y += sj*w4.y; ef.z += sj*w4.z; ef.w += sj*w4.w;
        }

        const float dh = (l < 16) ? den0 : den1;
        const float4 s4 = S4[(size_t)n * 32 + l];
        float4 o;
        if (dh > 0.f) {
            const float r = 1.0f / dh;
            o.x = (wv.x + ef.x) * r + s4.x;
            o.y = (wv.y + ef.y) * r + s4.y;
            o.z = (wv.z + ef.z) * r + s4.z;
            o.w = (wv.w + ef.w) * r + s4.w;
        } else {
            o = s4;
        }
        ((float4*)outp)[(size_t)n * 32 + l] = o;
        if (do_bn) {
            bsum.x += o.x; bsum.y += o.y; bsum.z += o.z; bsum.w += o.w;
            bssq.x += o.x*o.x; bssq.y += o.y*o.y; bssq.z += o.z*o.z; bssq.w += o.w*o.w;
        }
    }

    if (do_bn) {
        __syncthreads();
        float* red = WeS;
        const int t8 = tid * 8;
        red[t8+0]=bsum.x; red[t8+1]=bsum.y; red[t8+2]=bsum.z; red[t8+3]=bsum.w;
        red[t8+4]=bssq.x; red[t8+5]=bssq.y; red[t8+6]=bssq.z; red[t8+7]=bssq.w;
        __syncthreads();
        if (g == 0) {
            float a[8] = {0,0,0,0,0,0,0,0};
            for (int gg = 0; gg < 8; ++gg) {
                const float* r2 = &red[(gg*32 + l)*8];
                #pragma unroll
                for (int kk = 0; kk < 8; ++kk) a[kk] += r2[kk];
            }
            #pragma unroll
            for (int kk = 0; kk < 4; ++kk) {
                atomicAdd(&bn_sum[4*l + kk], a[kk]);
                atomicAdd(&bn_ssq[4*l + kk], a[4 + kk]);
            }
        }
    }
}

// ======================= BN =======================
__global__ void bn_stats_kernel(const float* __restrict__ bn_sum,
                                const float* __restrict__ bn_ssq,
                                float* __restrict__ mu, float* __restrict__ inv, int N)
{
    int c = threadIdx.x;
    float m = bn_sum[c] / (float)N;
    float var = bn_ssq[c] / (float)N - m * m;
    var = fmaxf(var, 0.f);
    mu[c] = m;
    inv[c] = rsqrtf(var + 1e-5f);
}

__global__ __launch_bounds__(256) void bn_apply_kernel(
    const float* __restrict__ pre, const float* __restrict__ mu,
    const float* __restrict__ inv, const float* __restrict__ gw,
    const float* __restrict__ bw, float* __restrict__ h, size_t total)
{
    size_t i = (size_t)blockIdx.x * 256 + threadIdx.x;
    const size_t stride = (size_t)gridDim.x * 256;
    for (; i < total; i += stride) {
        int c = (int)(i & 127);
        float val = (pre[i] - mu[c]) * inv[c] * gw[c] + bw[c];
        h[i] = fmaxf(val, 0.f);
    }
}

// =========================================================================
extern "C" void kernel_launch(void* const* d_in, const int* in_sizes, int n_in,
                              void* d_out, int out_size, void* d_ws, size_t ws_size,
                              hipStream_t stream)
{
    const float* x   = (const float*)d_in[0];
    const float* lu  = (const float*)d_in[1];
    const int*   ei  = (const int*)d_in[2];
    const float* t   = (const float*)d_in[3];
    const float* msg = (const float*)d_in[4];
    const float* tw  = (const float*)d_in[5];
    const float* tb  = (const float*)d_in[6];
    const float* bng = (const float*)d_in[7];
    const float* bnb = (const float*)d_in[8];
    const float* Wq1 = (const float*)d_in[9];  const float* bq1 = (const float*)d_in[10];
    const float* Wk1 = (const float*)d_in[11]; const float* bk1 = (const float*)d_in[12];
    const float* Wv1 = (const float*)d_in[13]; const float* bv1 = (const float*)d_in[14];
    const float* We1 = (const float*)d_in[15];
    const float* Ws1 = (const float*)d_in[16]; const float* bs1 = (const float*)d_in[17];
    const float* Wq2 = (const float*)d_in[18]; const float* bq2 = (const float*)d_in[19];
    const float* Wk2 = (const float*)d_in[20]; const float* bk2 = (const float*)d_in[21];
    const float* Wv2 = (const float*)d_in[22]; const float* bv2 = (const float*)d_in[23];
    const float* We2 = (const float*)d_in[24];
    const float* Ws2 = (const float*)d_in[25]; const float* bs2 = (const float*)d_in[26];

    const int N = in_sizes[0] / DD;
    const int E = in_sizes[3];
    const size_t NM = (size_t)N * DD;

    float* f   = (float*)d_ws;
    float* qb  = f;
    float* kb  = qb + NM;
    float* vb  = kb + NM;
    float* sb  = vb + NM;
    float* ub  = sb + NM;            // 2*NM
    float* pre = ub + 2 * NM;
    float* Wu  = pre + NM;           // 32768
    float* bu  = Wu + 32768;         // 256
    float* bsum = bu + 256;
    float* bssq = bsum + 128;
    float* muv  = bssq + 128;
    float* invv = muv + 128;
    int* cnt       = (int*)(invv + 128);
    int* row_start = cnt + N;        // N+1
    int* cursor    = row_start + N + 1;
    char* tail0 = (char*)(cursor + N);
    size_t off = (((size_t)(tail0 - (char*)d_ws)) + 255) & ~(size_t)255;

    // PRE layout: srcp[E] int, eaA[E*32] ushort, eaB[E*32] uint
    size_t need_pre = off + (size_t)E * 4 + (size_t)E * 64 + (size_t)E * 128 + 1024;
    const bool use_pre = (ws_size >= need_pre);

    int* srcp = (int*)((char*)d_ws + off);
    ushort_t* eaA = (ushort_t*)((char*)d_ws + off + (size_t)E * 4);
    uint_t*   eaB = (uint_t*)((char*)d_ws + off + (size_t)E * 4 + (size_t)E * 64);
    // FB layout (overlapping): se[E] int2, relp[E] float
    int2*  se   = (int2*)((char*)d_ws + off);
    float* relp = (float*)((char*)d_ws + off + (size_t)E * 8);

    const int EB = (E + 255) / 256;

    // ---- CSR (shared by both layers) ----
    hipMemsetAsync(cnt, 0, (size_t)N * sizeof(int), stream);
    hist_kernel<<<EB, 256, 0, stream>>>(ei, cnt, E);
    scan_kernel<<<1, 1024, 0, stream>>>(cnt, row_start, cursor, N);
    if (use_pre) {
        scatter_pre_kernel<<<(E + 7) / 8, 256, 0, stream>>>(
            ei, lu, t, msg, tw, tb, cursor, srcp, eaA, eaB, E);
    } else {
        scatter_fb_kernel<<<EB, 256, 0, stream>>>(ei, lu, t, cursor, se, relp, E);
    }

    dim3 gemmGrid((N + 31) / 32, 6);

    // ---------------- layer 1 ----------------
    build_wu_kernel<<<128, 256, 0, stream>>>(Wq1, bq1, We1, Wu, bu);
    gemm6_kernel<<<gemmGrid, 256, 0, stream>>>(
        x, Wq1, Wk1, Wv1, Ws1, Wu, Wu + 16384,
        bq1, bk1, bv1, bs1, bu, bu + 128,
        qb, kb, vb, sb, ub, ub + 128, N);
    hipMemsetAsync(bsum, 0, 256 * sizeof(float), stream);
    if (use_pre)
        node_attn_kernel<1><<<3072, 256, 0, stream>>>(
            row_start, srcp, eaA, eaB, se, relp, msg, tw, tb,
            qb, kb, vb, ub, We1, sb, pre, bsum, bssq, N, 1);
    else
        node_attn_kernel<0><<<3072, 256, 0, stream>>>(
            row_start, srcp, eaA, eaB, se, relp, msg, tw, tb,
            qb, kb, vb, ub, We1, sb, pre, bsum, bssq, N, 1);
    bn_stats_kernel<<<1, 128, 0, stream>>>(bsum, bssq, muv, invv, N);
    bn_apply_kernel<<<2048, 256, 0, stream>>>(pre, muv, invv, bng, bnb, pre, NM);

    // ---------------- layer 2 ----------------
    build_wu_kernel<<<128, 256, 0, stream>>>(Wq2, bq2, We2, Wu, bu);
    gemm6_kernel<<<gemmGrid, 256, 0, stream>>>(
        pre, Wq2, Wk2, Wv2, Ws2, Wu, Wu + 16384,
        bq2, bk2, bv2, bs2, bu, bu + 128,
        qb, kb, vb, sb, ub, ub + 128, N);
    if (use_pre)
        node_attn_kernel<1><<<3072, 256, 0, stream>>>(
            row_start, srcp, eaA, eaB, se, relp, msg, tw, tb,
            qb, kb, vb, ub, We2, sb, (float*)d_out, nullptr, nullptr, N, 0);
    else
        node_attn_kernel<0><<<3072, 256, 0, stream>>>(
            row_start, srcp, eaA, eaB, se, relp, msg, tw, tb,
            qb, kb, vb, ub, We2, sb, (float*)d_out, nullptr, nullptr, N, 0);
}

// Round 5
// 1131.923 us; speedup vs baseline: 1.2655x; 1.2655x over previous
//
#include <hip/hip_runtime.h>
#include <math.h>

#define DD 128
typedef unsigned short ushort_t;
typedef unsigned int uint_t;

// ---------------- DPP wave-reduction helpers -------------------
template<int CTRL>
__device__ __forceinline__ float dppAdd(float x) {
    int y = __builtin_amdgcn_update_dpp(0, __float_as_int(x), CTRL, 0xF, 0xF, true);
    return x + __int_as_float(y);
}
// sum over 16-lane rows (result in every lane of the row)
__device__ __forceinline__ float red16(float x) {
    x = dppAdd<0xB1>(x);   // quad_perm xor1
    x = dppAdd<0x4E>(x);   // quad_perm xor2
    x = dppAdd<0x141>(x);  // row_half_mirror
    x = dppAdd<0x140>(x);  // row_mirror
    return x;
}

__device__ __forceinline__ ushort_t f2bf(float f) {
    uint_t u = __float_as_uint(f);
    u += 0x7FFFu + ((u >> 16) & 1u);
    return (ushort_t)(u >> 16);
}
__device__ __forceinline__ uint_t packbf(float a, float b) {
    return (uint_t)f2bf(a) | ((uint_t)f2bf(b) << 16);
}
__device__ __forceinline__ float bflo(uint_t u) { return __uint_as_float(u << 16); }
__device__ __forceinline__ float bfhi(uint_t u) { return __uint_as_float(u & 0xFFFF0000u); }

// ======================= CSR build (once per call) =======================
__global__ __launch_bounds__(256) void hist_kernel(const int* __restrict__ ei,
                                                   int* __restrict__ cnt, int E) {
    int i = blockIdx.x * 256 + threadIdx.x;
    if (i < E) atomicAdd(&cnt[ei[E + i]], 1);
}

__global__ __launch_bounds__(1024) void scan_kernel(const int* __restrict__ cnt,
                                                    int* __restrict__ row_start,
                                                    int* __restrict__ cursor, int N) {
    __shared__ int part[1024];
    const int tid = threadIdx.x;
    const int chunk = (N + 1023) >> 10;
    const int lo = min(N, tid * chunk);
    const int hi = min(N, lo + chunk);
    int s = 0;
    for (int i = lo; i < hi; ++i) s += cnt[i];
    part[tid] = s;
    __syncthreads();
    for (int off = 1; off < 1024; off <<= 1) {
        int val = 0;
        if (tid >= off) val = part[tid - off];
        __syncthreads();
        part[tid] += val;
        __syncthreads();
    }
    int run = (tid == 0) ? 0 : part[tid - 1];
    for (int i = lo; i < hi; ++i) {
        row_start[i] = run; cursor[i] = run;
        run += cnt[i];
    }
    if (tid == 1023) row_start[N] = part[1023];
}

// group-per-edge: writes se(src,eid) + relp; PRE also writes bf16 msg stream
template<int PRE>
__global__ __launch_bounds__(256) void scatter_kernel(
    const int* __restrict__ ei, const float* __restrict__ lu, const float* __restrict__ t,
    const float* __restrict__ msg, int* __restrict__ cursor,
    int2* __restrict__ se, float* __restrict__ relp, uint_t* __restrict__ eaB, int E)
{
    const int g = threadIdx.x >> 5, l = threadIdx.x & 31;
    int i = blockIdx.x * 8 + g;
    if (i >= E) return;
    const int s = ei[i], d = ei[E + i];
    int pos = 0;
    if (l == 0) pos = atomicAdd(&cursor[d], 1);
    pos = __shfl(pos, 0, 32);
    if (PRE) {
        const float2 m2 = ((const float2*)msg)[(size_t)i * 32 + l];
        eaB[(size_t)pos * 32 + l] = packbf(m2.x, m2.y);
    }
    if (l == 0) { se[pos] = make_int2(s, i); relp[pos] = lu[s] - t[i]; }
}

// ======================= Wu = Wq @ B per head, lane-friendly layout ======
// u[n][h][col], col = l*8+j; dim(j): j<2 -> cos 2l+j (We row 2l+j);
// j in 2..5 -> msg 4l+(j-2) (We row 32+4l+j-2); j=6,7 unused (0).
__global__ __launch_bounds__(256) void build_wu_kernel(
    const float* __restrict__ Wq, const float* __restrict__ bq,
    const float* __restrict__ We, float* __restrict__ Wu, float* __restrict__ bu)
{
    int idx = blockIdx.x * 256 + threadIdx.x;   // [0, 32768)
    int h = idx >> 14;
    int r = (idx >> 7) & 127;
    int col = idx & 127;
    int lh = col >> 3, j = col & 7;
    int row = (j < 2) ? (2 * lh + j) : (j < 6 ? (32 + 4 * lh + (j - 2)) : -1);
    float s = 0.f, sb = 0.f;
    if (row >= 0) {
        for (int c = 0; c < 64; ++c) {
            float wv = We[row * 128 + h * 64 + c];
            s += Wq[r * 128 + h * 64 + c] * wv;
            if (r == 0) sb += bq[h * 64 + c] * wv;
        }
    }
    Wu[(h * 128 + r) * 128 + col] = s;
    if (r == 0) bu[h * 128 + col] = sb;
}

// ======================= fused 6-way node GEMM (K=128, N=128) ============
// which: 0=q(f32) 1=k(bf16->kvb) 2=v(bf16->kvb) 3=skip(f32) 4=u0 5=u1
__global__ __launch_bounds__(256) void gemm6_kernel(
    const float* __restrict__ X,
    const float* __restrict__ W0, const float* __restrict__ W1,
    const float* __restrict__ W2, const float* __restrict__ W3,
    const float* __restrict__ W4, const float* __restrict__ W5,
    const float* __restrict__ b0, const float* __restrict__ b1,
    const float* __restrict__ b2, const float* __restrict__ b3,
    const float* __restrict__ b4, const float* __restrict__ b5,
    float* __restrict__ O0, uint_t* __restrict__ kvb,
    float* __restrict__ O3, float* __restrict__ O4, float* __restrict__ O5, int M)
{
    __shared__ float Xs[32 * 128];
    __shared__ float Wsh[128 * 128];
    const int which = blockIdx.y;
    const float* W; const float* bias;
    switch (which) {
        case 0: W = W0; bias = b0; break;
        case 1: W = W1; bias = b1; break;
        case 2: W = W2; bias = b2; break;
        case 3: W = W3; bias = b3; break;
        case 4: W = W4; bias = b4; break;
        default: W = W5; bias = b5; break;
    }
    const int tid = threadIdx.x;
    const int m0 = blockIdx.x * 32;

    {
        const float4* Wg = (const float4*)W;
        float4* Wl = (float4*)Wsh;
        #pragma unroll
        for (int i = 0; i < 16; ++i) Wl[tid + i * 256] = Wg[tid + i * 256];
    }
    {
        float4* Xl = (float4*)Xs;
        const float4* Xg = (const float4*)X;
        #pragma unroll
        for (int i = 0; i < 4; ++i) {
            int f = tid + i * 256;
            int r = f >> 5, c4 = f & 31;
            int row = m0 + r;
            float4 val = make_float4(0.f, 0.f, 0.f, 0.f);
            if (row < M) val = Xg[(size_t)row * 32 + c4];
            Xl[f] = val;
        }
    }
    __syncthreads();

    const int tr = tid >> 5, tc = tid & 31;
    const int r0 = tr * 4, c0 = tc * 4;
    float acc[4][4] = {};
    #pragma unroll 4
    for (int kk = 0; kk < 128; ++kk) {
        float4 bb = *(const float4*)&Wsh[kk * 128 + c0];
        #pragma unroll
        for (int i = 0; i < 4; ++i) {
            float a = Xs[(r0 + i) * 128 + kk];
            acc[i][0] += a * bb.x; acc[i][1] += a * bb.y;
            acc[i][2] += a * bb.z; acc[i][3] += a * bb.w;
        }
    }
    float4 bias4 = *(const float4*)&bias[c0];
    if (which == 1 || which == 2) {
        const int voff = (which == 2) ? 32 : 0;
        uint2* KV = (uint2*)kvb;
        #pragma unroll
        for (int i = 0; i < 4; ++i) {
            int row = m0 + r0 + i;
            if (row < M) {
                KV[(size_t)row * 64 + voff + tc] =
                    make_uint2(packbf(acc[i][0] + bias4.x, acc[i][1] + bias4.y),
                               packbf(acc[i][2] + bias4.z, acc[i][3] + bias4.w));
            }
        }
    } else {
        float* O; int ostr;
        if (which == 0) { O = O0; ostr = 32; }
        else if (which == 3) { O = O3; ostr = 32; }
        else if (which == 4) { O = O4; ostr = 64; }
        else { O = O5; ostr = 64; }
        #pragma unroll
        for (int i = 0; i < 4; ++i) {
            int row = m0 + r0 + i;
            if (row < M) {
                float4 o;
                o.x = acc[i][0] + bias4.x; o.y = acc[i][1] + bias4.y;
                o.z = acc[i][2] + bias4.z; o.w = acc[i][3] + bias4.w;
                ((float4*)O)[(size_t)row * ostr + tc] = o;
            }
        }
    }
}

// ======================= node-centric attention ==========================
// One 32-lane group per node; two independent 16-lane halves (one head each).
// No LDS, no cross-16 exchange; 2-chunk software pipeline of gathers.
template<int PRE>
__global__ __launch_bounds__(256) void node_attn_kernel(
    const int* __restrict__ row_start, const int2* __restrict__ se,
    const float* __restrict__ relp, const uint_t* __restrict__ eaB,
    const float* __restrict__ msg,
    const float* __restrict__ time_w, const float* __restrict__ time_b,
    const float* __restrict__ q, const uint_t* __restrict__ kvb,
    const float* __restrict__ u, float* __restrict__ nodeAcc, int N)
{
    const int tid = threadIdx.x;
    const int g = tid >> 5, l = tid & 31;
    const int lh = l & 15;
    const int h = l >> 4;
    const int n = blockIdx.x * 8 + g;
    if (n >= N) return;

    const float twA = time_w[2 * lh], twB = time_w[2 * lh + 1];
    const float tbA = time_b[2 * lh], tbB = time_b[2 * lh + 1];
    const int e0 = row_start[n], e1 = row_start[n + 1];
    const float4 q4 = ((const float4*)q)[(size_t)n * 32 + l];
    const float4 u0 = ((const float4*)u)[(size_t)n * 64 + h * 32 + lh * 2];
    const float4 u1 = ((const float4*)u)[(size_t)n * 64 + h * 32 + lh * 2 + 1];
    const uint2* KV2 = (const uint2*)kvb;
    const uint2* EB2 = (const uint2*)eaB;

    float4 wv = {0, 0, 0, 0};
    float sA = 0, sB = 0, s0 = 0, s1 = 0, s2 = 0, s3 = 0, den = 0;

    struct Ch { int src[4]; float rel[4]; uint2 eb[4]; float4 mf[4]; uint2 kk[4]; uint2 vv[4]; };
    Ch cur, nxt;

    auto LOAD_META = [&](Ch& c, int b) {
        #pragma unroll
        for (int j = 0; j < 4; ++j) {
            int idx = b + j; idx = idx < e1 ? idx : e1 - 1;
            int2 s2 = se[idx];
            c.src[j] = s2.x;
            c.rel[j] = relp[idx];
            if (PRE) c.eb[j] = EB2[(size_t)idx * 16 + lh];
            else     c.mf[j] = ((const float4*)msg)[(size_t)s2.y * 16 + lh];
        }
    };
    auto LOAD_GATHER = [&](Ch& c) {
        #pragma unroll
        for (int j = 0; j < 4; ++j) {
            c.kk[j] = KV2[(size_t)c.src[j] * 64 + l];
            c.vv[j] = KV2[(size_t)c.src[j] * 64 + 32 + l];
        }
    };
    auto PROCESS = [&](Ch& c, int b) {
        #pragma unroll
        for (int j = 0; j < 4; ++j) {
            float cA = __cosf(c.rel[j] * twA + tbA);
            float cB = __cosf(c.rel[j] * twB + tbB);
            float m0, m1, m2, m3;
            if (PRE) {
                m0 = bflo(c.eb[j].x); m1 = bfhi(c.eb[j].x);
                m2 = bflo(c.eb[j].y); m3 = bfhi(c.eb[j].y);
            } else {
                m0 = c.mf[j].x; m1 = c.mf[j].y; m2 = c.mf[j].z; m3 = c.mf[j].w;
            }
            float k0 = bflo(c.kk[j].x), k1 = bfhi(c.kk[j].x);
            float k2 = bflo(c.kk[j].y), k3 = bfhi(c.kk[j].y);
            float p = q4.x * k0 + q4.y * k1 + q4.z * k2 + q4.w * k3
                    + cA * u0.x + cB * u0.y + m0 * u0.z + m1 * u0.w
                    + m2 * u1.x + m3 * u1.y;
            p = red16(p);
            float w = __expf(p * 0.125f);
            if (b + j >= e1) w = 0.f;
            den += w;
            float v0 = bflo(c.vv[j].x), v1 = bfhi(c.vv[j].x);
            float v2 = bflo(c.vv[j].y), v3 = bfhi(c.vv[j].y);
            wv.x += w * v0; wv.y += w * v1; wv.z += w * v2; wv.w += w * v3;
            sA += w * cA; sB += w * cB;
            s0 += w * m0; s1 += w * m1; s2 += w * m2; s3 += w * m3;
        }
    };

    if (e0 < e1) {
        LOAD_META(cur, e0);
        LOAD_GATHER(cur);
        for (int base = e0; base < e1; base += 4) {
            const bool more = (base + 4) < e1;
            if (more) LOAD_META(nxt, base + 4);
            PROCESS(cur, base);
            if (more) { LOAD_GATHER(nxt); cur = nxt; }
        }
    }
    float4* NA = (float4*)nodeAcc;
    NA[(size_t)n * 96 + l] = wv;
    NA[(size_t)n * 96 + 32 + l] = make_float4(sA, sB, s0, s1);
    NA[(size_t)n * 96 + 64 + l] = make_float4(s2, s3, den, 0.f);
}

// ======================= node finish: out = (wv + sea@We)/den + skip =====
// 16 nodes per block share one pass over We (96x128, from L2).
__global__ __launch_bounds__(256) void ef_finish_kernel(
    const float* __restrict__ nodeAcc, const float* __restrict__ We,
    const float* __restrict__ sbuf, float* __restrict__ outp,
    float* __restrict__ bn_sum, float* __restrict__ bn_ssq, int N, int do_bn)
{
    __shared__ float seaL[16][2][100];
    __shared__ float denL[16][2];
    __shared__ float red[4][16][16];
    const int tid = threadIdx.x;
    const int n0 = blockIdx.x * 16;
    const float4* NA4 = (const float4*)nodeAcc;

    #pragma unroll
    for (int it = 0; it < 4; ++it) {
        int f = tid + it * 256;          // [0,1024)
        int i2 = f >> 6, s = f & 63;
        int lsub = s & 31, half = s >> 5;
        int h2 = lsub >> 4, lh2 = lsub & 15;
        float4 val = {0, 0, 0, 0};
        if (n0 + i2 < N) val = NA4[(size_t)(n0 + i2) * 96 + 32 + half * 32 + lsub];
        if (half == 0) {
            seaL[i2][h2][2 * lh2] = val.x;  seaL[i2][h2][2 * lh2 + 1] = val.y;
            seaL[i2][h2][32 + 4 * lh2] = val.z; seaL[i2][h2][32 + 4 * lh2 + 1] = val.w;
        } else {
            seaL[i2][h2][32 + 4 * lh2 + 2] = val.x; seaL[i2][h2][32 + 4 * lh2 + 3] = val.y;
            if (lh2 == 0) denL[i2][h2] = val.z;
        }
    }
    __syncthreads();

    const int i = tid >> 4, p = tid & 15, h = p >> 3;
    const int n = n0 + i;
    const float4* We4 = (const float4*)We;
    float4 a0 = {0, 0, 0, 0}, a1 = {0, 0, 0, 0};
    if (n < N) { a0 = NA4[(size_t)n * 96 + 2 * p]; a1 = NA4[(size_t)n * 96 + 2 * p + 1]; }
    #pragma unroll 8
    for (int j = 0; j < 96; ++j) {
        float sj = seaL[i][h][j];
        float4 w0 = We4[j * 32 + 2 * p], w1 = We4[j * 32 + 2 * p + 1];
        a0.x += sj * w0.x; a0.y += sj * w0.y; a0.z += sj * w0.z; a0.w += sj * w0.w;
        a1.x += sj * w1.x; a1.y += sj * w1.y; a1.z += sj * w1.z; a1.w += sj * w1.w;
    }
    float4 sk0 = {0, 0, 0, 0}, sk1 = {0, 0, 0, 0};
    if (n < N) {
        sk0 = ((const float4*)sbuf)[(size_t)n * 32 + 2 * p];
        sk1 = ((const float4*)sbuf)[(size_t)n * 32 + 2 * p + 1];
    }
    const float dn = denL[i][h];
    float4 o0, o1;
    if (dn > 0.f) {
        const float r = 1.0f / dn;
        o0.x = a0.x * r + sk0.x; o0.y = a0.y * r + sk0.y;
        o0.z = a0.z * r + sk0.z; o0.w = a0.w * r + sk0.w;
        o1.x = a1.x * r + sk1.x; o1.y = a1.y * r + sk1.y;
        o1.z = a1.z * r + sk1.z; o1.w = a1.w * r + sk1.w;
    } else { o0 = sk0; o1 = sk1; }
    if (n < N) {
        ((float4*)outp)[(size_t)n * 32 + 2 * p] = o0;
        ((float4*)outp)[(size_t)n * 32 + 2 * p + 1] = o1;
    }

    if (do_bn) {
        if (n >= N) { o0 = make_float4(0,0,0,0); o1 = make_float4(0,0,0,0); }
        auto rs = [&](float x, int c) {
            x += __shfl_xor(x, 16); x += __shfl_xor(x, 32);
            if ((tid & 63) < 16) red[tid >> 6][tid & 15][c] = x;
        };
        rs(o0.x, 0); rs(o0.y, 1); rs(o0.z, 2); rs(o0.w, 3);
        rs(o1.x, 4); rs(o1.y, 5); rs(o1.z, 6); rs(o1.w, 7);
        rs(o0.x * o0.x, 8);  rs(o0.y * o0.y, 9);  rs(o0.z * o0.z, 10); rs(o0.w * o0.w, 11);
        rs(o1.x * o1.x, 12); rs(o1.y * o1.y, 13); rs(o1.z * o1.z, 14); rs(o1.w * o1.w, 15);
        __syncthreads();
        int pp = tid >> 4, cc = tid & 15;
        float tot = red[0][pp][cc] + red[1][pp][cc] + red[2][pp][cc] + red[3][pp][cc];
        int ch = pp * 8 + (cc & 7);
        if (cc < 8) atomicAdd(&bn_sum[ch], tot);
        else        atomicAdd(&bn_ssq[ch], tot);
    }
}

// ======================= BN =======================
__global__ void bn_stats_kernel(const float* __restrict__ bn_sum,
                                const float* __restrict__ bn_ssq,
                                float* __restrict__ mu, float* __restrict__ inv, int N)
{
    int c = threadIdx.x;
    float m = bn_sum[c] / (float)N;
    float var = bn_ssq[c] / (float)N - m * m;
    var = fmaxf(var, 0.f);
    mu[c] = m;
    inv[c] = rsqrtf(var + 1e-5f);
}

__global__ __launch_bounds__(256) void bn_apply_kernel(
    const float* __restrict__ pre, const float* __restrict__ mu,
    const float* __restrict__ inv, const float* __restrict__ gw,
    const float* __restrict__ bw, float* __restrict__ h, size_t total)
{
    size_t i = (size_t)blockIdx.x * 256 + threadIdx.x;
    const size_t stride = (size_t)gridDim.x * 256;
    for (; i < total; i += stride) {
        int c = (int)(i & 127);
        float val = (pre[i] - mu[c]) * inv[c] * gw[c] + bw[c];
        h[i] = fmaxf(val, 0.f);
    }
}

// =========================================================================
extern "C" void kernel_launch(void* const* d_in, const int* in_sizes, int n_in,
                              void* d_out, int out_size, void* d_ws, size_t ws_size,
                              hipStream_t stream)
{
    const float* x   = (const float*)d_in[0];
    const float* lu  = (const float*)d_in[1];
    const int*   ei  = (const int*)d_in[2];
    const float* t   = (const float*)d_in[3];
    const float* msg = (const float*)d_in[4];
    const float* tw  = (const float*)d_in[5];
    const float* tb  = (const float*)d_in[6];
    const float* bng = (const float*)d_in[7];
    const float* bnb = (const float*)d_in[8];
    const float* Wq1 = (const float*)d_in[9];  const float* bq1 = (const float*)d_in[10];
    const float* Wk1 = (const float*)d_in[11]; const float* bk1 = (const float*)d_in[12];
    const float* Wv1 = (const float*)d_in[13]; const float* bv1 = (const float*)d_in[14];
    const float* We1 = (const float*)d_in[15];
    const float* Ws1 = (const float*)d_in[16]; const float* bs1 = (const float*)d_in[17];
    const float* Wq2 = (const float*)d_in[18]; const float* bq2 = (const float*)d_in[19];
    const float* Wk2 = (const float*)d_in[20]; const float* bk2 = (const float*)d_in[21];
    const float* Wv2 = (const float*)d_in[22]; const float* bv2 = (const float*)d_in[23];
    const float* We2 = (const float*)d_in[24];
    const float* Ws2 = (const float*)d_in[25]; const float* bs2 = (const float*)d_in[26];

    const int N = in_sizes[0] / DD;
    const int E = in_sizes[3];
    const size_t NM = (size_t)N * DD;

    float* f   = (float*)d_ws;
    float* qb  = f;                       // NM
    float* sb  = qb + NM;                 // NM
    float* ub  = sb + NM;                 // 2*NM  [N][2][128]
    float* pre = ub + 2 * NM;             // NM
    uint_t* kvb = (uint_t*)(pre + NM);    // N*128 uints (k bf16 | v bf16)
    float* nodeAcc = (float*)(kvb + (size_t)N * 128);   // N*384 floats
    float* Wu  = nodeAcc + (size_t)N * 384;             // 32768
    float* bu  = Wu + 32768;              // 256
    float* bsum = bu + 256;               // 128
    float* bssq = bsum + 128;             // 128
    float* muv  = bssq + 128;             // 128
    float* invv = muv + 128;              // 128
    int* cnt       = (int*)(invv + 128);  // N
    int* row_start = cnt + N;             // N+1
    int* cursor    = row_start + N + 1;   // N
    char* tail0 = (char*)(cursor + N);
    size_t off = (((size_t)(tail0 - (char*)d_ws)) + 255) & ~(size_t)255;

    int2*  se   = (int2*)((char*)d_ws + off);                       // E
    float* relp = (float*)((char*)d_ws + off + (size_t)E * 8);      // E
    uint_t* eaB = (uint_t*)((char*)d_ws + off + (size_t)E * 12);    // E*32
    size_t need_pre = off + (size_t)E * 12 + (size_t)E * 128 + 1024;
    const bool use_pre = (ws_size >= need_pre);

    const int EB = (E + 255) / 256;

    // ---- CSR (shared by both layers) ----
    hipMemsetAsync(cnt, 0, (size_t)N * sizeof(int), stream);
    hist_kernel<<<EB, 256, 0, stream>>>(ei, cnt, E);
    scan_kernel<<<1, 1024, 0, stream>>>(cnt, row_start, cursor, N);
    if (use_pre)
        scatter_kernel<1><<<(E + 7) / 8, 256, 0, stream>>>(ei, lu, t, msg, cursor, se, relp, eaB, E);
    else
        scatter_kernel<0><<<(E + 7) / 8, 256, 0, stream>>>(ei, lu, t, msg, cursor, se, relp, eaB, E);

    dim3 gemmGrid((N + 31) / 32, 6);
    const int attnGrid = (N + 7) / 8;
    const int finGrid = (N + 15) / 16;

    // ---------------- layer 1 ----------------
    build_wu_kernel<<<128, 256, 0, stream>>>(Wq1, bq1, We1, Wu, bu);
    gemm6_kernel<<<gemmGrid, 256, 0, stream>>>(
        x, Wq1, Wk1, Wv1, Ws1, Wu, Wu + 16384,
        bq1, bk1, bv1, bs1, bu, bu + 128,
        qb, kvb, sb, ub, ub + 128, N);
    if (use_pre)
        node_attn_kernel<1><<<attnGrid, 256, 0, stream>>>(
            row_start, se, relp, eaB, msg, tw, tb, qb, kvb, ub, nodeAcc, N);
    else
        node_attn_kernel<0><<<attnGrid, 256, 0, stream>>>(
            row_start, se, relp, eaB, msg, tw, tb, qb, kvb, ub, nodeAcc, N);
    hipMemsetAsync(bsum, 0, 256 * sizeof(float), stream);
    ef_finish_kernel<<<finGrid, 256, 0, stream>>>(
        nodeAcc, We1, sb, pre, bsum, bssq, N, 1);
    bn_stats_kernel<<<1, 128, 0, stream>>>(bsum, bssq, muv, invv, N);
    bn_apply_kernel<<<2048, 256, 0, stream>>>(pre, muv, invv, bng, bnb, pre, NM);

    // ---------------- layer 2 ----------------
    build_wu_kernel<<<128, 256, 0, stream>>>(Wq2, bq2, We2, Wu, bu);
    gemm6_kernel<<<gemmGrid, 256, 0, stream>>>(
        pre, Wq2, Wk2, Wv2, Ws2, Wu, Wu + 16384,
        bq2, bk2, bv2, bs2, bu, bu + 128,
        qb, kvb, sb, ub, ub + 128, N);
    if (use_pre)
        node_attn_kernel<1><<<attnGrid, 256, 0, stream>>>(
            row_start, se, relp, eaB, msg, tw, tb, qb, kvb, ub, nodeAcc, N);
    else
        node_attn_kernel<0><<<attnGrid, 256, 0, stream>>>(
            row_start, se, relp, eaB, msg, tw, tb, qb, kvb, ub, nodeAcc, N);
    ef_finish_kernel<<<finGrid, 256, 0, stream>>>(
        nodeAcc, We2, sb, (float*)d_out, nullptr, nullptr, N, 0);
}

// Round 6
// 1096.757 us; speedup vs baseline: 1.3060x; 1.0321x over previous
//
#include <hip/hip_runtime.h>
#include <math.h>

#define DD 128
typedef unsigned short ushort_t;
typedef unsigned int uint_t;

// ---------------- DPP wave-reduction helpers -------------------
template<int CTRL>
__device__ __forceinline__ float dppAdd(float x) {
    int y = __builtin_amdgcn_update_dpp(0, __float_as_int(x), CTRL, 0xF, 0xF, true);
    return x + __int_as_float(y);
}
// sum over 16-lane rows (result in every lane of the row)
__device__ __forceinline__ float red16(float x) {
    x = dppAdd<0xB1>(x);   // quad_perm xor1
    x = dppAdd<0x4E>(x);   // quad_perm xor2
    x = dppAdd<0x141>(x);  // row_half_mirror
    x = dppAdd<0x140>(x);  // row_mirror
    return x;
}

__device__ __forceinline__ ushort_t f2bf(float f) {
    uint_t u = __float_as_uint(f);
    u += 0x7FFFu + ((u >> 16) & 1u);
    return (ushort_t)(u >> 16);
}
__device__ __forceinline__ uint_t packbf(float a, float b) {
    return (uint_t)f2bf(a) | ((uint_t)f2bf(b) << 16);
}
__device__ __forceinline__ float bflo(uint_t u) { return __uint_as_float(u << 16); }
__device__ __forceinline__ float bfhi(uint_t u) { return __uint_as_float(u & 0xFFFF0000u); }

// ======================= CSR build (once per call) =======================
__global__ __launch_bounds__(256) void hist_kernel(const int* __restrict__ ei,
                                                   int* __restrict__ cnt, int E) {
    int i = blockIdx.x * 256 + threadIdx.x;
    if (i < E) atomicAdd(&cnt[ei[E + i]], 1);
}

__global__ __launch_bounds__(1024) void scan_kernel(const int* __restrict__ cnt,
                                                    int* __restrict__ row_start,
                                                    int* __restrict__ cursor, int N) {
    __shared__ int part[1024];
    const int tid = threadIdx.x;
    const int chunk = (N + 1023) >> 10;
    const int lo = min(N, tid * chunk);
    const int hi = min(N, lo + chunk);
    int s = 0;
    for (int i = lo; i < hi; ++i) s += cnt[i];
    part[tid] = s;
    __syncthreads();
    for (int off = 1; off < 1024; off <<= 1) {
        int val = 0;
        if (tid >= off) val = part[tid - off];
        __syncthreads();
        part[tid] += val;
        __syncthreads();
    }
    int run = (tid == 0) ? 0 : part[tid - 1];
    for (int i = lo; i < hi; ++i) {
        row_start[i] = run; cursor[i] = run;
        run += cnt[i];
    }
    if (tid == 1023) row_start[N] = part[1023];
}

// meta scatter: one int4 record per edge (src, eid, rel_bits, 0)
__global__ __launch_bounds__(256) void scatter_fb_kernel(
    const int* __restrict__ ei, const float* __restrict__ lu, const float* __restrict__ t,
    int* __restrict__ cursor, int4* __restrict__ ser, int E)
{
    int i = blockIdx.x * 256 + threadIdx.x;
    if (i < E) {
        int s = ei[i], d = ei[E + i];
        int pos = atomicAdd(&cursor[d], 1);
        ser[pos] = make_int4(s, i, __float_as_int(lu[s] - t[i]), 0);
    }
}

// streaming msg f32 -> bf16 (edge order; gathered by eid in attn)
__global__ __launch_bounds__(256) void msg2bf_kernel(
    const float4* __restrict__ m4, uint2* __restrict__ o, size_t total4)
{
    size_t i = (size_t)blockIdx.x * 256 + threadIdx.x;
    const size_t stride = (size_t)gridDim.x * 256;
    for (; i < total4; i += stride) {
        float4 v = m4[i];
        o[i] = make_uint2(packbf(v.x, v.y), packbf(v.z, v.w));
    }
}

// ======================= Wu = Wq @ B per head, lane-friendly layout ======
__global__ __launch_bounds__(256) void build_wu_kernel(
    const float* __restrict__ Wq, const float* __restrict__ bq,
    const float* __restrict__ We, float* __restrict__ Wu, float* __restrict__ bu)
{
    int idx = blockIdx.x * 256 + threadIdx.x;   // [0, 32768)
    int h = idx >> 14;
    int r = (idx >> 7) & 127;
    int col = idx & 127;
    int lh = col >> 3, j = col & 7;
    int row = (j < 2) ? (2 * lh + j) : (j < 6 ? (32 + 4 * lh + (j - 2)) : -1);
    float s = 0.f, sb = 0.f;
    if (row >= 0) {
        for (int c = 0; c < 64; ++c) {
            float wv = We[row * 128 + h * 64 + c];
            s += Wq[r * 128 + h * 64 + c] * wv;
            if (r == 0) sb += bq[h * 64 + c] * wv;
        }
    }
    Wu[(h * 128 + r) * 128 + col] = s;
    if (r == 0) bu[h * 128 + col] = sb;
}

// ======================= fused 6-way node GEMM (K=128, N=128) ============
// which: 0=q(f32) 1=k(bf16->kvb) 2=v(bf16->kvb) 3=skip(f32) 4=u0 5=u1
__global__ __launch_bounds__(256) void gemm6_kernel(
    const float* __restrict__ X,
    const float* __restrict__ W0, const float* __restrict__ W1,
    const float* __restrict__ W2, const float* __restrict__ W3,
    const float* __restrict__ W4, const float* __restrict__ W5,
    const float* __restrict__ b0, const float* __restrict__ b1,
    const float* __restrict__ b2, const float* __restrict__ b3,
    const float* __restrict__ b4, const float* __restrict__ b5,
    float* __restrict__ O0, uint_t* __restrict__ kvb,
    float* __restrict__ O3, float* __restrict__ O4, float* __restrict__ O5, int M)
{
    __shared__ float Xs[32 * 128];
    __shared__ float Wsh[128 * 128];
    const int which = blockIdx.y;
    const float* W; const float* bias;
    switch (which) {
        case 0: W = W0; bias = b0; break;
        case 1: W = W1; bias = b1; break;
        case 2: W = W2; bias = b2; break;
        case 3: W = W3; bias = b3; break;
        case 4: W = W4; bias = b4; break;
        default: W = W5; bias = b5; break;
    }
    const int tid = threadIdx.x;
    const int m0 = blockIdx.x * 32;

    {
        const float4* Wg = (const float4*)W;
        float4* Wl = (float4*)Wsh;
        #pragma unroll
        for (int i = 0; i < 16; ++i) Wl[tid + i * 256] = Wg[tid + i * 256];
    }
    {
        float4* Xl = (float4*)Xs;
        const float4* Xg = (const float4*)X;
        #pragma unroll
        for (int i = 0; i < 4; ++i) {
            int f = tid + i * 256;
            int r = f >> 5, c4 = f & 31;
            int row = m0 + r;
            float4 val = make_float4(0.f, 0.f, 0.f, 0.f);
            if (row < M) val = Xg[(size_t)row * 32 + c4];
            Xl[f] = val;
        }
    }
    __syncthreads();

    const int tr = tid >> 5, tc = tid & 31;
    const int r0 = tr * 4, c0 = tc * 4;
    float acc[4][4] = {};
    #pragma unroll 4
    for (int kk = 0; kk < 128; ++kk) {
        float4 bb = *(const float4*)&Wsh[kk * 128 + c0];
        #pragma unroll
        for (int i = 0; i < 4; ++i) {
            float a = Xs[(r0 + i) * 128 + kk];
            acc[i][0] += a * bb.x; acc[i][1] += a * bb.y;
            acc[i][2] += a * bb.z; acc[i][3] += a * bb.w;
        }
    }
    float4 bias4 = *(const float4*)&bias[c0];
    if (which == 1 || which == 2) {
        const int voff = (which == 2) ? 32 : 0;
        uint2* KV = (uint2*)kvb;
        #pragma unroll
        for (int i = 0; i < 4; ++i) {
            int row = m0 + r0 + i;
            if (row < M) {
                KV[(size_t)row * 64 + voff + tc] =
                    make_uint2(packbf(acc[i][0] + bias4.x, acc[i][1] + bias4.y),
                               packbf(acc[i][2] + bias4.z, acc[i][3] + bias4.w));
            }
        }
    } else {
        float* O; int ostr;
        if (which == 0) { O = O0; ostr = 32; }
        else if (which == 3) { O = O3; ostr = 32; }
        else if (which == 4) { O = O4; ostr = 64; }
        else { O = O5; ostr = 64; }
        #pragma unroll
        for (int i = 0; i < 4; ++i) {
            int row = m0 + r0 + i;
            if (row < M) {
                float4 o;
                o.x = acc[i][0] + bias4.x; o.y = acc[i][1] + bias4.y;
                o.z = acc[i][2] + bias4.z; o.w = acc[i][3] + bias4.w;
                ((float4*)O)[(size_t)row * ostr + tc] = o;
            }
        }
    }
}

// ======================= node-centric attention ==========================
// One 32-lane group per node; two independent 16-lane halves (one head each).
// No LDS, no cross-16 exchange; 2-chunk software pipeline of gathers.
// PRE=1: gather bf16 msg (eaB2, L3-resident); PRE=0: gather f32 msg.
template<int PRE>
__global__ __launch_bounds__(256) void node_attn_kernel(
    const int* __restrict__ row_start, const int4* __restrict__ ser,
    const uint_t* __restrict__ eaB,
    const float* __restrict__ msg,
    const float* __restrict__ time_w, const float* __restrict__ time_b,
    const float* __restrict__ q, const uint_t* __restrict__ kvb,
    const float* __restrict__ u, float* __restrict__ nodeAcc, int N)
{
    const int tid = threadIdx.x;
    const int g = tid >> 5, l = tid & 31;
    const int lh = l & 15;
    const int h = l >> 4;
    const int n = blockIdx.x * 8 + g;
    if (n >= N) return;

    const float twA = time_w[2 * lh], twB = time_w[2 * lh + 1];
    const float tbA = time_b[2 * lh], tbB = time_b[2 * lh + 1];
    const int e0 = row_start[n], e1 = row_start[n + 1];
    const float4 q4 = ((const float4*)q)[(size_t)n * 32 + l];
    const float4 u0 = ((const float4*)u)[(size_t)n * 64 + h * 32 + lh * 2];
    const float4 u1 = ((const float4*)u)[(size_t)n * 64 + h * 32 + lh * 2 + 1];
    const uint2* KV2 = (const uint2*)kvb;
    const uint2* EB2 = (const uint2*)eaB;

    float4 wv = {0, 0, 0, 0};
    float sA = 0, sB = 0, s0 = 0, s1 = 0, s2 = 0, s3 = 0, den = 0;

    struct Ch { int src[4]; float rel[4]; uint2 eb[4]; float4 mf[4]; uint2 kk[4]; uint2 vv[4]; };
    Ch cur, nxt;

    auto LOAD_META = [&](Ch& c, int b) {
        #pragma unroll
        for (int j = 0; j < 4; ++j) {
            int idx = b + j; idx = idx < e1 ? idx : e1 - 1;
            int4 m = ser[idx];
            c.src[j] = m.x;
            c.rel[j] = __int_as_float(m.z);
            if (PRE) c.eb[j] = EB2[(size_t)m.y * 16 + lh];
            else     c.mf[j] = ((const float4*)msg)[(size_t)m.y * 16 + lh];
        }
    };
    auto LOAD_GATHER = [&](Ch& c) {
        #pragma unroll
        for (int j = 0; j < 4; ++j) {
            c.kk[j] = KV2[(size_t)c.src[j] * 64 + l];
            c.vv[j] = KV2[(size_t)c.src[j] * 64 + 32 + l];
        }
    };
    auto PROCESS = [&](Ch& c, int b) {
        #pragma unroll
        for (int j = 0; j < 4; ++j) {
            float cA = __cosf(c.rel[j] * twA + tbA);
            float cB = __cosf(c.rel[j] * twB + tbB);
            float m0, m1, m2, m3;
            if (PRE) {
                m0 = bflo(c.eb[j].x); m1 = bfhi(c.eb[j].x);
                m2 = bflo(c.eb[j].y); m3 = bfhi(c.eb[j].y);
            } else {
                m0 = c.mf[j].x; m1 = c.mf[j].y; m2 = c.mf[j].z; m3 = c.mf[j].w;
            }
            float k0 = bflo(c.kk[j].x), k1 = bfhi(c.kk[j].x);
            float k2 = bflo(c.kk[j].y), k3 = bfhi(c.kk[j].y);
            float p = q4.x * k0 + q4.y * k1 + q4.z * k2 + q4.w * k3
                    + cA * u0.x + cB * u0.y + m0 * u0.z + m1 * u0.w
                    + m2 * u1.x + m3 * u1.y;
            p = red16(p);
            float w = __expf(p * 0.125f);
            if (b + j >= e1) w = 0.f;
            den += w;
            float v0 = bflo(c.vv[j].x), v1 = bfhi(c.vv[j].x);
            float v2 = bflo(c.vv[j].y), v3 = bfhi(c.vv[j].y);
            wv.x += w * v0; wv.y += w * v1; wv.z += w * v2; wv.w += w * v3;
            sA += w * cA; sB += w * cB;
            s0 += w * m0; s1 += w * m1; s2 += w * m2; s3 += w * m3;
        }
    };

    if (e0 < e1) {
        LOAD_META(cur, e0);
        LOAD_GATHER(cur);
        for (int base = e0; base < e1; base += 4) {
            const bool more = (base + 4) < e1;
            if (more) LOAD_META(nxt, base + 4);
            PROCESS(cur, base);
            if (more) { LOAD_GATHER(nxt); cur = nxt; }
        }
    }
    float4* NA = (float4*)nodeAcc;
    NA[(size_t)n * 96 + l] = wv;
    NA[(size_t)n * 96 + 32 + l] = make_float4(sA, sB, s0, s1);
    NA[(size_t)n * 96 + 64 + l] = make_float4(s2, s3, den, 0.f);
}

// ======================= node finish: out = (wv + sea@We)/den + skip =====
// 16 nodes per block share one pass over We (96x128, from L2).
__global__ __launch_bounds__(256) void ef_finish_kernel(
    const float* __restrict__ nodeAcc, const float* __restrict__ We,
    const float* __restrict__ sbuf, float* __restrict__ outp,
    float* __restrict__ bn_sum, float* __restrict__ bn_ssq, int N, int do_bn)
{
    __shared__ float seaL[16][2][100];
    __shared__ float denL[16][2];
    __shared__ float red[4][16][16];
    const int tid = threadIdx.x;
    const int n0 = blockIdx.x * 16;
    const float4* NA4 = (const float4*)nodeAcc;

    #pragma unroll
    for (int it = 0; it < 4; ++it) {
        int f = tid + it * 256;          // [0,1024)
        int i2 = f >> 6, s = f & 63;
        int lsub = s & 31, half = s >> 5;
        int h2 = lsub >> 4, lh2 = lsub & 15;
        float4 val = {0, 0, 0, 0};
        if (n0 + i2 < N) val = NA4[(size_t)(n0 + i2) * 96 + 32 + half * 32 + lsub];
        if (half == 0) {
            seaL[i2][h2][2 * lh2] = val.x;  seaL[i2][h2][2 * lh2 + 1] = val.y;
            seaL[i2][h2][32 + 4 * lh2] = val.z; seaL[i2][h2][32 + 4 * lh2 + 1] = val.w;
        } else {
            seaL[i2][h2][32 + 4 * lh2 + 2] = val.x; seaL[i2][h2][32 + 4 * lh2 + 3] = val.y;
            if (lh2 == 0) denL[i2][h2] = val.z;
        }
    }
    __syncthreads();

    const int i = tid >> 4, p = tid & 15, h = p >> 3;
    const int n = n0 + i;
    const float4* We4 = (const float4*)We;
    float4 a0 = {0, 0, 0, 0}, a1 = {0, 0, 0, 0};
    if (n < N) { a0 = NA4[(size_t)n * 96 + 2 * p]; a1 = NA4[(size_t)n * 96 + 2 * p + 1]; }
    #pragma unroll 8
    for (int j = 0; j < 96; ++j) {
        float sj = seaL[i][h][j];
        float4 w0 = We4[j * 32 + 2 * p], w1 = We4[j * 32 + 2 * p + 1];
        a0.x += sj * w0.x; a0.y += sj * w0.y; a0.z += sj * w0.z; a0.w += sj * w0.w;
        a1.x += sj * w1.x; a1.y += sj * w1.y; a1.z += sj * w1.z; a1.w += sj * w1.w;
    }
    float4 sk0 = {0, 0, 0, 0}, sk1 = {0, 0, 0, 0};
    if (n < N) {
        sk0 = ((const float4*)sbuf)[(size_t)n * 32 + 2 * p];
        sk1 = ((const float4*)sbuf)[(size_t)n * 32 + 2 * p + 1];
    }
    const float dn = denL[i][h];
    float4 o0, o1;
    if (dn > 0.f) {
        const float r = 1.0f / dn;
        o0.x = a0.x * r + sk0.x; o0.y = a0.y * r + sk0.y;
        o0.z = a0.z * r + sk0.z; o0.w = a0.w * r + sk0.w;
        o1.x = a1.x * r + sk1.x; o1.y = a1.y * r + sk1.y;
        o1.z = a1.z * r + sk1.z; o1.w = a1.w * r + sk1.w;
    } else { o0 = sk0; o1 = sk1; }
    if (n < N) {
        ((float4*)outp)[(size_t)n * 32 + 2 * p] = o0;
        ((float4*)outp)[(size_t)n * 32 + 2 * p + 1] = o1;
    }

    if (do_bn) {
        if (n >= N) { o0 = make_float4(0,0,0,0); o1 = make_float4(0,0,0,0); }
        auto rs = [&](float x, int c) {
            x += __shfl_xor(x, 16); x += __shfl_xor(x, 32);
            if ((tid & 63) < 16) red[tid >> 6][tid & 15][c] = x;
        };
        rs(o0.x, 0); rs(o0.y, 1); rs(o0.z, 2); rs(o0.w, 3);
        rs(o1.x, 4); rs(o1.y, 5); rs(o1.z, 6); rs(o1.w, 7);
        rs(o0.x * o0.x, 8);  rs(o0.y * o0.y, 9);  rs(o0.z * o0.z, 10); rs(o0.w * o0.w, 11);
        rs(o1.x * o1.x, 12); rs(o1.y * o1.y, 13); rs(o1.z * o1.z, 14); rs(o1.w * o1.w, 15);
        __syncthreads();
        int pp = tid >> 4, cc = tid & 15;
        float tot = red[0][pp][cc] + red[1][pp][cc] + red[2][pp][cc] + red[3][pp][cc];
        int ch = pp * 8 + (cc & 7);
        if (cc < 8) atomicAdd(&bn_sum[ch], tot);
        else        atomicAdd(&bn_ssq[ch], tot);
    }
}

// ======================= BN =======================
__global__ void bn_stats_kernel(const float* __restrict__ bn_sum,
                                const float* __restrict__ bn_ssq,
                                float* __restrict__ mu, float* __restrict__ inv, int N)
{
    int c = threadIdx.x;
    float m = bn_sum[c] / (float)N;
    float var = bn_ssq[c] / (float)N - m * m;
    var = fmaxf(var, 0.f);
    mu[c] = m;
    inv[c] = rsqrtf(var + 1e-5f);
}

__global__ __launch_bounds__(256) void bn_apply_kernel(
    const float* __restrict__ pre, const float* __restrict__ mu,
    const float* __restrict__ inv, const float* __restrict__ gw,
    const float* __restrict__ bw, float* __restrict__ h, size_t total)
{
    size_t i = (size_t)blockIdx.x * 256 + threadIdx.x;
    const size_t stride = (size_t)gridDim.x * 256;
    for (; i < total; i += stride) {
        int c = (int)(i & 127);
        float val = (pre[i] - mu[c]) * inv[c] * gw[c] + bw[c];
        h[i] = fmaxf(val, 0.f);
    }
}

// =========================================================================
extern "C" void kernel_launch(void* const* d_in, const int* in_sizes, int n_in,
                              void* d_out, int out_size, void* d_ws, size_t ws_size,
                              hipStream_t stream)
{
    const float* x   = (const float*)d_in[0];
    const float* lu  = (const float*)d_in[1];
    const int*   ei  = (const int*)d_in[2];
    const float* t   = (const float*)d_in[3];
    const float* msg = (const float*)d_in[4];
    const float* tw  = (const float*)d_in[5];
    const float* tb  = (const float*)d_in[6];
    const float* bng = (const float*)d_in[7];
    const float* bnb = (const float*)d_in[8];
    const float* Wq1 = (const float*)d_in[9];  const float* bq1 = (const float*)d_in[10];
    const float* Wk1 = (const float*)d_in[11]; const float* bk1 = (const float*)d_in[12];
    const float* Wv1 = (const float*)d_in[13]; const float* bv1 = (const float*)d_in[14];
    const float* We1 = (const float*)d_in[15];
    const float* Ws1 = (const float*)d_in[16]; const float* bs1 = (const float*)d_in[17];
    const float* Wq2 = (const float*)d_in[18]; const float* bq2 = (const float*)d_in[19];
    const float* Wk2 = (const float*)d_in[20]; const float* bk2 = (const float*)d_in[21];
    const float* Wv2 = (const float*)d_in[22]; const float* bv2 = (const float*)d_in[23];
    const float* We2 = (const float*)d_in[24];
    const float* Ws2 = (const float*)d_in[25]; const float* bs2 = (const float*)d_in[26];

    const int N = in_sizes[0] / DD;
    const int E = in_sizes[3];
    const size_t NM = (size_t)N * DD;

    float* f   = (float*)d_ws;
    float* qb  = f;                       // NM
    float* sb  = qb + NM;                 // NM
    float* ub  = sb + NM;                 // 2*NM  [N][2][128]
    float* pre = ub + 2 * NM;             // NM
    uint_t* kvb = (uint_t*)(pre + NM);    // N*128 uints (k bf16 | v bf16)
    float* nodeAcc = (float*)(kvb + (size_t)N * 128);   // N*384 floats
    float* Wu  = nodeAcc + (size_t)N * 384;             // 32768
    float* bu  = Wu + 32768;              // 256
    float* bsum = bu + 256;               // 128
    float* bssq = bsum + 128;             // 128
    float* muv  = bssq + 128;             // 128
    float* invv = muv + 128;              // 128
    int* cnt       = (int*)(invv + 128);  // N
    int* row_start = cnt + N;             // N+1
    int* cursor    = row_start + N + 1;   // N
    char* tail0 = (char*)(cursor + N);
    size_t off = (((size_t)(tail0 - (char*)d_ws)) + 255) & ~(size_t)255;

    int4*   ser  = (int4*)((char*)d_ws + off);                      // E
    uint_t* eaB2 = (uint_t*)((char*)d_ws + off + (size_t)E * 16);   // E*32
    size_t need_pre = off + (size_t)E * 16 + (size_t)E * 128 + 1024;
    const bool use_pre = (ws_size >= need_pre);

    const int EB = (E + 255) / 256;

    // ---- CSR + edge-order bf16 msg (shared by both layers) ----
    hipMemsetAsync(cnt, 0, (size_t)N * sizeof(int), stream);
    hist_kernel<<<EB, 256, 0, stream>>>(ei, cnt, E);
    scan_kernel<<<1, 1024, 0, stream>>>(cnt, row_start, cursor, N);
    scatter_fb_kernel<<<EB, 256, 0, stream>>>(ei, lu, t, cursor, ser, E);
    if (use_pre)
        msg2bf_kernel<<<4096, 256, 0, stream>>>(
            (const float4*)msg, (uint2*)eaB2, (size_t)E * 16);

    dim3 gemmGrid((N + 31) / 32, 6);
    const int attnGrid = (N + 7) / 8;
    const int finGrid = (N + 15) / 16;

    // ---------------- layer 1 ----------------
    build_wu_kernel<<<128, 256, 0, stream>>>(Wq1, bq1, We1, Wu, bu);
    gemm6_kernel<<<gemmGrid, 256, 0, stream>>>(
        x, Wq1, Wk1, Wv1, Ws1, Wu, Wu + 16384,
        bq1, bk1, bv1, bs1, bu, bu + 128,
        qb, kvb, sb, ub, ub + 128, N);
    if (use_pre)
        node_attn_kernel<1><<<attnGrid, 256, 0, stream>>>(
            row_start, ser, eaB2, msg, tw, tb, qb, kvb, ub, nodeAcc, N);
    else
        node_attn_kernel<0><<<attnGrid, 256, 0, stream>>>(
            row_start, ser, eaB2, msg, tw, tb, qb, kvb, ub, nodeAcc, N);
    hipMemsetAsync(bsum, 0, 256 * sizeof(float), stream);
    ef_finish_kernel<<<finGrid, 256, 0, stream>>>(
        nodeAcc, We1, sb, pre, bsum, bssq, N, 1);
    bn_stats_kernel<<<1, 128, 0, stream>>>(bsum, bssq, muv, invv, N);
    bn_apply_kernel<<<2048, 256, 0, stream>>>(pre, muv, invv, bng, bnb, pre, NM);

    // ---------------- layer 2 ----------------
    build_wu_kernel<<<128, 256, 0, stream>>>(Wq2, bq2, We2, Wu, bu);
    gemm6_kernel<<<gemmGrid, 256, 0, stream>>>(
        pre, Wq2, Wk2, Wv2, Ws2, Wu, Wu + 16384,
        bq2, bk2, bv2, bs2, bu, bu + 128,
        qb, kvb, sb, ub, ub + 128, N);
    if (use_pre)
        node_attn_kernel<1><<<attnGrid, 256, 0, stream>>>(
            row_start, ser, eaB2, msg, tw, tb, qb, kvb, ub, nodeAcc, N);
    else
        node_attn_kernel<0><<<attnGrid, 256, 0, stream>>>(
            row_start, ser, eaB2, msg, tw, tb, qb, kvb, ub, nodeAcc, N);
    ef_finish_kernel<<<finGrid, 256, 0, stream>>>(
        nodeAcc, We2, sb, (float*)d_out, nullptr, nullptr, N, 0);
}

// Round 8
// 852.482 us; speedup vs baseline: 1.6803x; 1.2865x over previous
//
#include <hip/hip_runtime.h>
#include <math.h>

#define DD 128
typedef unsigned short ushort_t;
typedef unsigned int uint_t;
typedef __attribute__((ext_vector_type(8))) short bf16x8;
typedef __attribute__((ext_vector_type(4))) float f32x4;

// ---------------- DPP wave-reduction helpers -------------------
template<int CTRL>
__device__ __forceinline__ float dppAdd(float x) {
    int y = __builtin_amdgcn_update_dpp(0, __float_as_int(x), CTRL, 0xF, 0xF, true);
    return x + __int_as_float(y);
}
__device__ __forceinline__ float red16(float x) {
    x = dppAdd<0xB1>(x);   // quad_perm xor1
    x = dppAdd<0x4E>(x);   // quad_perm xor2
    x = dppAdd<0x141>(x);  // row_half_mirror
    x = dppAdd<0x140>(x);  // row_mirror
    return x;
}

__device__ __forceinline__ ushort_t f2bf(float f) {
    uint_t u = __float_as_uint(f);
    u += 0x7FFFu + ((u >> 16) & 1u);
    return (ushort_t)(u >> 16);
}
__device__ __forceinline__ uint_t packbf(float a, float b) {
    return (uint_t)f2bf(a) | ((uint_t)f2bf(b) << 16);
}
__device__ __forceinline__ float bflo(uint_t u) { return __uint_as_float(u << 16); }
__device__ __forceinline__ float bfhi(uint_t u) { return __uint_as_float(u & 0xFFFF0000u); }

// ======================= CSR build (once per call) =======================
__global__ __launch_bounds__(256) void hist_kernel(const int* __restrict__ ei,
                                                   int* __restrict__ cnt, int E) {
    int i = blockIdx.x * 256 + threadIdx.x;
    if (i < E) atomicAdd(&cnt[ei[E + i]], 1);
}

__global__ __launch_bounds__(1024) void scan_kernel(const int* __restrict__ cnt,
                                                    int* __restrict__ row_start,
                                                    int* __restrict__ cursor, int N) {
    __shared__ int part[1024];
    const int tid = threadIdx.x;
    const int chunk = (N + 1023) >> 10;
    const int lo = min(N, tid * chunk);
    const int hi = min(N, lo + chunk);
    int s = 0;
    for (int i = lo; i < hi; ++i) s += cnt[i];
    part[tid] = s;
    __syncthreads();
    for (int off = 1; off < 1024; off <<= 1) {
        int val = 0;
        if (tid >= off) val = part[tid - off];
        __syncthreads();
        part[tid] += val;
        __syncthreads();
    }
    int run = (tid == 0) ? 0 : part[tid - 1];
    for (int i = lo; i < hi; ++i) {
        row_start[i] = run; cursor[i] = run;
        run += cnt[i];
    }
    if (tid == 1023) row_start[N] = part[1023];
}

// meta scatter: one int4 record per edge (src, eid, rel_bits, 0)
__global__ __launch_bounds__(256) void scatter_fb_kernel(
    const int* __restrict__ ei, const float* __restrict__ lu, const float* __restrict__ t,
    int* __restrict__ cursor, int4* __restrict__ ser, int E)
{
    int i = blockIdx.x * 256 + threadIdx.x;
    if (i < E) {
        int s = ei[i], d = ei[E + i];
        int pos = atomicAdd(&cursor[d], 1);
        ser[pos] = make_int4(s, i, __float_as_int(lu[s] - t[i]), 0);
    }
}

// streaming f32 -> bf16 (4 at a time); used for msg and for x
__global__ __launch_bounds__(256) void msg2bf_kernel(
    const float4* __restrict__ m4, uint2* __restrict__ o, size_t total4)
{
    size_t i = (size_t)blockIdx.x * 256 + threadIdx.x;
    const size_t stride = (size_t)gridDim.x * 256;
    for (; i < total4; i += stride) {
        float4 v = m4[i];
        o[i] = make_uint2(packbf(v.x, v.y), packbf(v.z, v.w));
    }
}

// ======================= Wu = Wq @ B per head, lane-friendly layout ======
__global__ __launch_bounds__(256) void build_wu_kernel(
    const float* __restrict__ Wq, const float* __restrict__ bq,
    const float* __restrict__ We, float* __restrict__ Wu, float* __restrict__ bu)
{
    int idx = blockIdx.x * 256 + threadIdx.x;   // [0, 32768)
    int h = idx >> 14;
    int r = (idx >> 7) & 127;
    int col = idx & 127;
    int lh = col >> 3, j = col & 7;
    int row = (j < 2) ? (2 * lh + j) : (j < 6 ? (32 + 4 * lh + (j - 2)) : -1);
    float s = 0.f, sb = 0.f;
    if (row >= 0) {
        for (int c = 0; c < 64; ++c) {
            float wv = We[row * 128 + h * 64 + c];
            s += Wq[r * 128 + h * 64 + c] * wv;
            if (r == 0) sb += bq[h * 64 + c] * wv;
        }
    }
    Wu[(h * 128 + r) * 128 + col] = s;
    if (r == 0) bu[h * 128 + col] = sb;
}

// ============== pack 6 weight mats -> transposed bf16 Wcat_t[768][128] ===
__global__ __launch_bounds__(256) void pack_w_kernel(
    const float* __restrict__ Wq, const float* __restrict__ Wk,
    const float* __restrict__ Wv, const float* __restrict__ Wsk,
    const float* __restrict__ Wu,
    const float* __restrict__ bq, const float* __restrict__ bk,
    const float* __restrict__ bv, const float* __restrict__ bsk,
    const float* __restrict__ bu,
    ushort_t* __restrict__ wcat, float* __restrict__ bcat)
{
    int idx = blockIdx.x * 256 + threadIdx.x;   // [0, 98304)
    int cg = idx >> 7, k = idx & 127;
    int which = cg >> 7, col = cg & 127;
    float v, b;
    switch (which) {
        case 0:  v = Wq[k * 128 + col];          b = bq[col];       break;
        case 1:  v = Wk[k * 128 + col];          b = bk[col];       break;
        case 2:  v = Wv[k * 128 + col];          b = bv[col];       break;
        case 3:  v = Wsk[k * 128 + col];         b = bsk[col];      break;
        case 4:  v = Wu[k * 128 + col];          b = bu[col];       break;
        default: v = Wu[(128 + k) * 128 + col];  b = bu[128 + col]; break;
    }
    wcat[cg * 128 + k] = f2bf(v);
    if (k == 0) bcat[cg] = b;
}

// ======================= MFMA 6-way node GEMM (bf16 in, K=128) ===========
// Tile 64 rows x 128 cols; grid.y = cb in 0..5 selects output.
__global__ __launch_bounds__(256) void mfma_gemm_kernel(
    const uint4* __restrict__ xb4,   // [M][16] uint4 (128 bf16/row)
    const uint4* __restrict__ wc4,   // [768][16]
    const float* __restrict__ bcat,  // [768]
    float* __restrict__ qb, ushort_t* __restrict__ kvbS,
    float* __restrict__ sb, float* __restrict__ ub, int M)
{
    __shared__ ushort_t Xs[64 * 136];
    __shared__ ushort_t Wt[128 * 136];
    const int tid = threadIdx.x;
    const int m0 = blockIdx.x * 64;
    const int cb = blockIdx.y;

    // stage X tile: 64 rows x 16 uint4/row = 1024 writes
    #pragma unroll
    for (int i = 0; i < 4; ++i) {
        int f = tid + i * 256, r = f >> 4, ch = f & 15;
        uint4 val = make_uint4(0, 0, 0, 0);
        if (m0 + r < M) val = xb4[(size_t)(m0 + r) * 16 + ch];
        *(uint4*)&Xs[r * 136 + ch * 8] = val;
    }
    // stage W^T tile: 128 rows x 16 uint4/row = 2048 writes
    #pragma unroll
    for (int i = 0; i < 8; ++i) {
        int f = tid + i * 256, r = f >> 4, ch = f & 15;
        *(uint4*)&Wt[r * 136 + ch * 8] = wc4[(size_t)(cb * 128 + r) * 16 + ch];
    }
    __syncthreads();

    const int w = tid >> 6, l = tid & 63, rl = l & 15, g = l >> 4;
    f32x4 acc[8];
    #pragma unroll
    for (int c = 0; c < 8; ++c) acc[c] = (f32x4){0.f, 0.f, 0.f, 0.f};
    const ushort_t* Ar = &Xs[(w * 16 + rl) * 136];
    #pragma unroll
    for (int kk = 0; kk < 4; ++kk) {
        bf16x8 a = *(const bf16x8*)&Ar[kk * 32 + g * 8];
        #pragma unroll
        for (int c = 0; c < 8; ++c) {
            bf16x8 b = *(const bf16x8*)&Wt[(c * 16 + rl) * 136 + kk * 32 + g * 8];
            acc[c] = __builtin_amdgcn_mfma_f32_16x16x32_bf16(a, b, acc[c], 0, 0, 0);
        }
    }
    float bias_c[8];
    #pragma unroll
    for (int c = 0; c < 8; ++c) bias_c[c] = bcat[cb * 128 + c * 16 + rl];

    float* fp = qb; int stride = 128, off = 0; bool isbf = false;
    switch (cb) {
        case 0: fp = qb; stride = 128; off = 0;   break;
        case 3: fp = sb; stride = 128; off = 0;   break;
        case 4: fp = ub; stride = 256; off = 0;   break;
        case 5: fp = ub; stride = 256; off = 128; break;
        case 1: isbf = true; off = 0;   break;
        default: isbf = true; off = 128; break;   // cb==2 -> v
    }
    const int R0 = m0 + w * 16 + g * 4;
    #pragma unroll
    for (int r = 0; r < 4; ++r) {
        int R = R0 + r;
        if (R < M) {
            if (isbf) {
                #pragma unroll
                for (int c = 0; c < 8; ++c)
                    kvbS[(size_t)R * 256 + off + c * 16 + rl] = f2bf(acc[c][r] + bias_c[c]);
            } else {
                #pragma unroll
                for (int c = 0; c < 8; ++c)
                    fp[(size_t)R * stride + off + c * 16 + rl] = acc[c][r] + bias_c[c];
            }
        }
    }
}

// ======================= node-centric attention ==========================
template<int PRE>
__global__ __launch_bounds__(256) void node_attn_kernel(
    const int* __restrict__ row_start, const int4* __restrict__ ser,
    const uint_t* __restrict__ eaB,
    const float* __restrict__ msg,
    const float* __restrict__ time_w, const float* __restrict__ time_b,
    const float* __restrict__ q, const uint_t* __restrict__ kvb,
    const float* __restrict__ u, float* __restrict__ nodeAcc, int N)
{
    const int tid = threadIdx.x;
    const int g = tid >> 5, l = tid & 31;
    const int lh = l & 15;
    const int h = l >> 4;
    const int n = blockIdx.x * 8 + g;
    if (n >= N) return;

    const float twA = time_w[2 * lh], twB = time_w[2 * lh + 1];
    const float tbA = time_b[2 * lh], tbB = time_b[2 * lh + 1];
    const int e0 = row_start[n], e1 = row_start[n + 1];
    const float4 q4 = ((const float4*)q)[(size_t)n * 32 + l];
    const float4 u0 = ((const float4*)u)[(size_t)n * 64 + h * 32 + lh * 2];
    const float4 u1 = ((const float4*)u)[(size_t)n * 64 + h * 32 + lh * 2 + 1];
    const uint2* KV2 = (const uint2*)kvb;
    const uint2* EB2 = (const uint2*)eaB;

    float4 wv = {0, 0, 0, 0};
    float sA = 0, sB = 0, s0 = 0, s1 = 0, s2 = 0, s3 = 0, den = 0;

    struct Ch { int src[4]; float rel[4]; uint2 eb[4]; float4 mf[4]; uint2 kk[4]; uint2 vv[4]; };
    Ch cur, nxt;

    auto LOAD_META = [&](Ch& c, int b) {
        #pragma unroll
        for (int j = 0; j < 4; ++j) {
            int idx = b + j; idx = idx < e1 ? idx : e1 - 1;
            int4 m = ser[idx];
            c.src[j] = m.x;
            c.rel[j] = __int_as_float(m.z);
            if (PRE) c.eb[j] = EB2[(size_t)m.y * 16 + lh];
            else     c.mf[j] = ((const float4*)msg)[(size_t)m.y * 16 + lh];
        }
    };
    auto LOAD_GATHER = [&](Ch& c) {
        #pragma unroll
        for (int j = 0; j < 4; ++j) {
            c.kk[j] = KV2[(size_t)c.src[j] * 64 + l];
            c.vv[j] = KV2[(size_t)c.src[j] * 64 + 32 + l];
        }
    };
    auto PROCESS = [&](Ch& c, int b) {
        #pragma unroll
        for (int j = 0; j < 4; ++j) {
            float cA = __cosf(c.rel[j] * twA + tbA);
            float cB = __cosf(c.rel[j] * twB + tbB);
            float m0, m1, m2, m3;
            if (PRE) {
                m0 = bflo(c.eb[j].x); m1 = bfhi(c.eb[j].x);
                m2 = bflo(c.eb[j].y); m3 = bfhi(c.eb[j].y);
            } else {
                m0 = c.mf[j].x; m1 = c.mf[j].y; m2 = c.mf[j].z; m3 = c.mf[j].w;
            }
            float k0 = bflo(c.kk[j].x), k1 = bfhi(c.kk[j].x);
            float k2 = bflo(c.kk[j].y), k3 = bfhi(c.kk[j].y);
            float p = q4.x * k0 + q4.y * k1 + q4.z * k2 + q4.w * k3
                    + cA * u0.x + cB * u0.y + m0 * u0.z + m1 * u0.w
                    + m2 * u1.x + m3 * u1.y;
            p = red16(p);
            float w = __expf(p * 0.125f);
            if (b + j >= e1) w = 0.f;
            den += w;
            float v0 = bflo(c.vv[j].x), v1 = bfhi(c.vv[j].x);
            float v2 = bflo(c.vv[j].y), v3 = bfhi(c.vv[j].y);
            wv.x += w * v0; wv.y += w * v1; wv.z += w * v2; wv.w += w * v3;
            sA += w * cA; sB += w * cB;
            s0 += w * m0; s1 += w * m1; s2 += w * m2; s3 += w * m3;
        }
    };

    if (e0 < e1) {
        LOAD_META(cur, e0);
        LOAD_GATHER(cur);
        for (int base = e0; base < e1; base += 4) {
            const bool more = (base + 4) < e1;
            if (more) LOAD_META(nxt, base + 4);
            PROCESS(cur, base);
            if (more) { LOAD_GATHER(nxt); cur = nxt; }
        }
    }
    float4* NA = (float4*)nodeAcc;
    NA[(size_t)n * 96 + l] = wv;
    NA[(size_t)n * 96 + 32 + l] = make_float4(sA, sB, s0, s1);
    NA[(size_t)n * 96 + 64 + l] = make_float4(s2, s3, den, 0.f);
}

// ======================= node finish: out = (wv + sea@We)/den + skip =====
__global__ __launch_bounds__(256) void ef_finish_kernel(
    const float* __restrict__ nodeAcc, const float* __restrict__ We,
    const float* __restrict__ sbuf, float* __restrict__ outp,
    float* __restrict__ bn_sum, float* __restrict__ bn_ssq, int N, int do_bn)
{
    __shared__ float seaL[16][2][100];
    __shared__ float denL[16][2];
    __shared__ float red[4][16][16];
    const int tid = threadIdx.x;
    const int n0 = blockIdx.x * 16;
    const float4* NA4 = (const float4*)nodeAcc;

    #pragma unroll
    for (int it = 0; it < 4; ++it) {
        int f = tid + it * 256;          // [0,1024)
        int i2 = f >> 6, s = f & 63;
        int lsub = s & 31, half = s >> 5;
        int h2 = lsub >> 4, lh2 = lsub & 15;
        float4 val = {0, 0, 0, 0};
        if (n0 + i2 < N) val = NA4[(size_t)(n0 + i2) * 96 + 32 + half * 32 + lsub];
        if (half == 0) {
            seaL[i2][h2][2 * lh2] = val.x;  seaL[i2][h2][2 * lh2 + 1] = val.y;
            seaL[i2][h2][32 + 4 * lh2] = val.z; seaL[i2][h2][32 + 4 * lh2 + 1] = val.w;
        } else {
            seaL[i2][h2][32 + 4 * lh2 + 2] = val.x; seaL[i2][h2][32 + 4 * lh2 + 3] = val.y;
            if (lh2 == 0) denL[i2][h2] = val.z;
        }
    }
    __syncthreads();

    const int i = tid >> 4, p = tid & 15, h = p >> 3;
    const int n = n0 + i;
    const float4* We4 = (const float4*)We;
    float4 a0 = {0, 0, 0, 0}, a1 = {0, 0, 0, 0};
    if (n < N) { a0 = NA4[(size_t)n * 96 + 2 * p]; a1 = NA4[(size_t)n * 96 + 2 * p + 1]; }
    #pragma unroll 8
    for (int j = 0; j < 96; ++j) {
        float sj = seaL[i][h][j];
        float4 w0 = We4[j * 32 + 2 * p], w1 = We4[j * 32 + 2 * p + 1];
        a0.x += sj * w0.x; a0.y += sj * w0.y; a0.z += sj * w0.z; a0.w += sj * w0.w;
        a1.x += sj * w1.x; a1.y += sj * w1.y; a1.z += sj * w1.z; a1.w += sj * w1.w;
    }
    float4 sk0 = {0, 0, 0, 0}, sk1 = {0, 0, 0, 0};
    if (n < N) {
        sk0 = ((const float4*)sbuf)[(size_t)n * 32 + 2 * p];
        sk1 = ((const float4*)sbuf)[(size_t)n * 32 + 2 * p + 1];
    }
    const float dn = denL[i][h];
    float4 o0, o1;
    if (dn > 0.f) {
        const float r = 1.0f / dn;
        o0.x = a0.x * r + sk0.x; o0.y = a0.y * r + sk0.y;
        o0.z = a0.z * r + sk0.z; o0.w = a0.w * r + sk0.w;
        o1.x = a1.x * r + sk1.x; o1.y = a1.y * r + sk1.y;
        o1.z = a1.z * r + sk1.z; o1.w = a1.w * r + sk1.w;
    } else { o0 = sk0; o1 = sk1; }
    if (n < N) {
        ((float4*)outp)[(size_t)n * 32 + 2 * p] = o0;
        ((float4*)outp)[(size_t)n * 32 + 2 * p + 1] = o1;
    }

    if (do_bn) {
        if (n >= N) { o0 = make_float4(0,0,0,0); o1 = make_float4(0,0,0,0); }
        auto rs = [&](float x, int c) {
            x += __shfl_xor(x, 16); x += __shfl_xor(x, 32);
            if ((tid & 63) < 16) red[tid >> 6][tid & 15][c] = x;
        };
        rs(o0.x, 0); rs(o0.y, 1); rs(o0.z, 2); rs(o0.w, 3);
        rs(o1.x, 4); rs(o1.y, 5); rs(o1.z, 6); rs(o1.w, 7);
        rs(o0.x * o0.x, 8);  rs(o0.y * o0.y, 9);  rs(o0.z * o0.z, 10); rs(o0.w * o0.w, 11);
        rs(o1.x * o1.x, 12); rs(o1.y * o1.y, 13); rs(o1.z * o1.z, 14); rs(o1.w * o1.w, 15);
        __syncthreads();
        int pp = tid >> 4, cc = tid & 15;
        float tot = red[0][pp][cc] + red[1][pp][cc] + red[2][pp][cc] + red[3][pp][cc];
        int ch = pp * 8 + (cc & 7);
        if (cc < 8) atomicAdd(&bn_sum[ch], tot);
        else        atomicAdd(&bn_ssq[ch], tot);
    }
}

// ======================= BN =======================
__global__ void bn_stats_kernel(const float* __restrict__ bn_sum,
                                const float* __restrict__ bn_ssq,
                                float* __restrict__ mu, float* __restrict__ inv, int N)
{
    int c = threadIdx.x;
    float m = bn_sum[c] / (float)N;
    float var = bn_ssq[c] / (float)N - m * m;
    var = fmaxf(var, 0.f);
    mu[c] = m;
    inv[c] = rsqrtf(var + 1e-5f);
}

// BN apply + ReLU, emitting bf16 directly (layer-2 GEMM input)
__global__ __launch_bounds__(256) void bn_apply_kernel(
    const float* __restrict__ pre, const float* __restrict__ mu,
    const float* __restrict__ inv, const float* __restrict__ gw,
    const float* __restrict__ bw, ushort_t* __restrict__ xb, size_t total)
{
    size_t i = (size_t)blockIdx.x * 256 + threadIdx.x;
    const size_t stride = (size_t)gridDim.x * 256;
    for (; i < total; i += stride) {
        int c = (int)(i & 127);
        float val = (pre[i] - mu[c]) * inv[c] * gw[c] + bw[c];
        xb[i] = f2bf(fmaxf(val, 0.f));
    }
}

// =========================================================================
extern "C" void kernel_launch(void* const* d_in, const int* in_sizes, int n_in,
                              void* d_out, int out_size, void* d_ws, size_t ws_size,
                              hipStream_t stream)
{
    const float* x   = (const float*)d_in[0];
    const float* lu  = (const float*)d_in[1];
    const int*   ei  = (const int*)d_in[2];
    const float* t   = (const float*)d_in[3];
    const float* msg = (const float*)d_in[4];
    const float* tw  = (const float*)d_in[5];
    const float* tb  = (const float*)d_in[6];
    const float* bng = (const float*)d_in[7];
    const float* bnb = (const float*)d_in[8];
    const float* Wq1 = (const float*)d_in[9];  const float* bq1 = (const float*)d_in[10];
    const float* Wk1 = (const float*)d_in[11]; const float* bk1 = (const float*)d_in[12];
    const float* Wv1 = (const float*)d_in[13]; const float* bv1 = (const float*)d_in[14];
    const float* We1 = (const float*)d_in[15];
    const float* Ws1 = (const float*)d_in[16]; const float* bs1 = (const float*)d_in[17];
    const float* Wq2 = (const float*)d_in[18]; const float* bq2 = (const float*)d_in[19];
    const float* Wk2 = (const float*)d_in[20]; const float* bk2 = (const float*)d_in[21];
    const float* Wv2 = (const float*)d_in[22]; const float* bv2 = (const float*)d_in[23];
    const float* We2 = (const float*)d_in[24];
    const float* Ws2 = (const float*)d_in[25]; const float* bs2 = (const float*)d_in[26];

    const int N = in_sizes[0] / DD;
    const int E = in_sizes[3];
    const size_t NM = (size_t)N * DD;

    float* f   = (float*)d_ws;
    float* qb  = f;                       // NM
    float* sb  = qb + NM;                 // NM
    float* ub  = sb + NM;                 // 2*NM  [N][2][128]
    float* pre = ub + 2 * NM;             // NM
    uint_t* kvb = (uint_t*)(pre + NM);    // N*128 uints (k bf16 | v bf16)
    ushort_t* xb = (ushort_t*)(kvb + (size_t)N * 128);   // N*128 bf16
    float* nodeAcc = (float*)((char*)xb + (size_t)N * 128 * sizeof(ushort_t)); // N*384 floats
    ushort_t* wcat = (ushort_t*)(nodeAcc + (size_t)N * 384);  // 98304
    float* bcat = (float*)(wcat + 98304); // 768
    float* Wu  = bcat + 768;              // 32768
    float* bu  = Wu + 32768;              // 256
    float* bsum = bu + 256;               // 128
    float* bssq = bsum + 128;             // 128
    float* muv  = bssq + 128;             // 128
    float* invv = muv + 128;              // 128
    int* cnt       = (int*)(invv + 128);  // N
    int* row_start = cnt + N;             // N+1
    int* cursor    = row_start + N + 1;   // N
    char* tail0 = (char*)(cursor + N);
    size_t off = (((size_t)(tail0 - (char*)d_ws)) + 255) & ~(size_t)255;

    int4*   ser  = (int4*)((char*)d_ws + off);                      // E
    uint_t* eaB2 = (uint_t*)((char*)d_ws + off + (size_t)E * 16);   // E*32
    size_t need_pre = off + (size_t)E * 16 + (size_t)E * 128 + 1024;
    const bool use_pre = (ws_size >= need_pre);

    const int EB = (E + 255) / 256;

    // ---- CSR + edge-order bf16 msg (shared by both layers) ----
    hipMemsetAsync(cnt, 0, (size_t)N * sizeof(int), stream);
    hist_kernel<<<EB, 256, 0, stream>>>(ei, cnt, E);
    scan_kernel<<<1, 1024, 0, stream>>>(cnt, row_start, cursor, N);
    scatter_fb_kernel<<<EB, 256, 0, stream>>>(ei, lu, t, cursor, ser, E);
    if (use_pre)
        msg2bf_kernel<<<4096, 256, 0, stream>>>(
            (const float4*)msg, (uint2*)eaB2, (size_t)E * 16);
    // x -> bf16 (layer-1 GEMM input)
    msg2bf_kernel<<<2048, 256, 0, stream>>>(
        (const float4*)x, (uint2*)xb, NM / 4);

    dim3 gemmGrid((N + 63) / 64, 6);
    const int attnGrid = (N + 7) / 8;
    const int finGrid = (N + 15) / 16;

    // ---------------- layer 1 ----------------
    build_wu_kernel<<<128, 256, 0, stream>>>(Wq1, bq1, We1, Wu, bu);
    pack_w_kernel<<<384, 256, 0, stream>>>(
        Wq1, Wk1, Wv1, Ws1, Wu, bq1, bk1, bv1, bs1, bu, wcat, bcat);
    mfma_gemm_kernel<<<gemmGrid, 256, 0, stream>>>(
        (const uint4*)xb, (const uint4*)wcat, bcat,
        qb, (ushort_t*)kvb, sb, ub, N);
    if (use_pre)
        node_attn_kernel<1><<<attnGrid, 256, 0, stream>>>(
            row_start, ser, eaB2, msg, tw, tb, qb, kvb, ub, nodeAcc, N);
    else
        node_attn_kernel<0><<<attnGrid, 256, 0, stream>>>(
            row_start, ser, eaB2, msg, tw, tb, qb, kvb, ub, nodeAcc, N);
    hipMemsetAsync(bsum, 0, 256 * sizeof(float), stream);
    ef_finish_kernel<<<finGrid, 256, 0, stream>>>(
        nodeAcc, We1, sb, pre, bsum, bssq, N, 1);
    bn_stats_kernel<<<1, 128, 0, stream>>>(bsum, bssq, muv, invv, N);
    bn_apply_kernel<<<2048, 256, 0, stream>>>(pre, muv, invv, bng, bnb, xb, NM);

    // ---------------- layer 2 ----------------
    build_wu_kernel<<<128, 256, 0, stream>>>(Wq2, bq2, We2, Wu, bu);
    pack_w_kernel<<<384, 256, 0, stream>>>(
        Wq2, Wk2, Wv2, Ws2, Wu, bq2, bk2, bv2, bs2, bu, wcat, bcat);
    mfma_gemm_kernel<<<gemmGrid, 256, 0, stream>>>(
        (const uint4*)xb, (const uint4*)wcat, bcat,
        qb, (ushort_t*)kvb, sb, ub, N);
    if (use_pre)
        node_attn_kernel<1><<<attnGrid, 256, 0, stream>>>(
            row_start, ser, eaB2, msg, tw, tb, qb, kvb, ub, nodeAcc, N);
    else
        node_attn_kernel<0><<<attnGrid, 256, 0, stream>>>(
            row_start, ser, eaB2, msg, tw, tb, qb, kvb, ub, nodeAcc, N);
    ef_finish_kernel<<<finGrid, 256, 0, stream>>>(
        nodeAcc, We2, sb, (float*)d_out, nullptr, nullptr, N, 0);
}